// Round 3
// baseline (620.055 us; speedup 1.0000x reference)
//
#include <hip/hip_runtime.h>

#define DH 128

typedef float  floatx4 __attribute__((ext_vector_type(4)));
typedef float  floatx2 __attribute__((ext_vector_type(2)));
typedef short  shortx8 __attribute__((ext_vector_type(8)));

__device__ __forceinline__ unsigned short f2bf(float f) {
    unsigned u = __builtin_bit_cast(unsigned, f);
    u += 0x7fffu + ((u >> 16) & 1u);
    return (unsigned short)(u >> 16);
}
__device__ __forceinline__ float fast_silu(float x) {
    return x * __builtin_amdgcn_rcpf(1.f + __expf(-x));
}

// ---- prep: split-concat transpose  dst[l][j][k] = src[l][(j>>7)*128+k][j&127], bf16 ----
__global__ void prep_split_kernel(const float* __restrict__ src, unsigned short* __restrict__ dst,
                                  int L, int SR) {
    int idx = blockIdx.x * 256 + threadIdx.x;
    int tot = L * 256 * 128;
    if (idx >= tot) return;
    int l = idx / (256 * 128);
    int rem = idx - l * 256 * 128;
    int j = rem >> 7;
    int k = rem & 127;
    int srow = ((j >> 7) << 7) + k;
    dst[idx] = f2bf(src[(size_t)l * SR * 128 + (size_t)srow * 128 + (j & 127)]);
}

// ---- prep: plain transpose  dst[l][j][k] = src[l][k][j], bf16 ----
__global__ void prep_T_kernel(const float* __restrict__ src, unsigned short* __restrict__ dst,
                              int L, int K) {
    int idx = blockIdx.x * 256 + threadIdx.x;
    int tot = L * 128 * K;
    if (idx >= tot) return;
    int l = idx / (128 * K);
    int rem = idx - l * 128 * K;
    int j = rem / K;
    int k = rem - j * K;
    dst[idx] = f2bf(src[(size_t)l * K * 128 + (size_t)k * 128 + j]);
}

// ---- node encoder: h = silu(x@w1+b1)@w2+b2 ----
__global__ __launch_bounds__(128)
void node_enc_kernel(const float* __restrict__ xyr,
                     const float* __restrict__ w1, const float* __restrict__ b1,
                     const float* __restrict__ w2, const float* __restrict__ b2,
                     float* __restrict__ h, unsigned short* __restrict__ hbf, int N) {
    __shared__ float xs[16][3];
    __shared__ float hid[16][DH];
    int n0 = blockIdx.x * 16;
    int t = threadIdx.x;
    if (t < 48) {
        int i = t / 3, j = t - 3 * (t / 3);
        int n = n0 + i; if (n >= N) n = N - 1;
        xs[i][j] = xyr[3 * n + j];
    }
    __syncthreads();
    int col = t;
    float w10 = w1[col], w11 = w1[DH + col], w12 = w1[2 * DH + col];
    float bb = b1[col];
#pragma unroll
    for (int i = 0; i < 16; ++i) {
        float v = bb + xs[i][0] * w10 + xs[i][1] * w11 + xs[i][2] * w12;
        hid[i][col] = fast_silu(v);
    }
    __syncthreads();
    float a[16];
#pragma unroll
    for (int i = 0; i < 16; ++i) a[i] = b2[col];
    for (int j = 0; j < DH; ++j) {
        float wv = w2[j * DH + col];
#pragma unroll
        for (int i = 0; i < 16; ++i) a[i] += hid[i][j] * wv;
    }
    for (int i = 0; i < 16; ++i) {
        int n = n0 + i;
        if (n < N) {
            h[(size_t)n * DH + col] = a[i];
            hbf[(size_t)n * DH + col] = f2bf(a[i]);
        }
    }
}

// ---- CSR build ----
__global__ void count_kernel(const int* __restrict__ dst, int* __restrict__ cnt, int E) {
    int e = blockIdx.x * 256 + threadIdx.x;
    if (e < E) atomicAdd(&cnt[dst[e]], 1);
}
__global__ __launch_bounds__(1024)
void scan_kernel(const int* __restrict__ cnt, int* __restrict__ rs, int* __restrict__ cursor,
                 float* __restrict__ cntf, int N) {
    __shared__ int ps[1024];
    const int CH = 16;
    int t = threadIdx.x;
    int base = t * CH;
    int loc[CH];
    int s = 0;
#pragma unroll
    for (int j = 0; j < CH; ++j) {
        int i = base + j;
        int v = (i < N) ? cnt[i] : 0;
        if (i < N) cntf[i] = (float)v;
        loc[j] = s; s += v;
    }
    ps[t] = s;
    __syncthreads();
    for (int off = 1; off < 1024; off <<= 1) {
        int v = (t >= off) ? ps[t - off] : 0;
        __syncthreads();
        ps[t] += v;
        __syncthreads();
    }
    int pre = (t > 0) ? ps[t - 1] : 0;
#pragma unroll
    for (int j = 0; j < CH; ++j) {
        int i = base + j;
        if (i < N) { int v = pre + loc[j]; rs[i] = v; cursor[i] = v; }
    }
    if (t == 0) rs[N] = ps[1023];
}
// ---- fill + edge prep fused: slot assignment + src idx + fp32 rbf row per CSR slot ----
__global__ void fill_kernel(const int* __restrict__ src, const int* __restrict__ dst,
                            int* __restrict__ cursor, const float* __restrict__ xyr,
                            int* __restrict__ esrc, float* __restrict__ rbfc, int E) {
    int e = blockIdx.x * 256 + threadIdx.x;
    if (e >= E) return;
    int s = src[e], d = dst[e];
    int p = atomicAdd(&cursor[d], 1);
    esrc[p] = s;
    float dx = xyr[3 * s] - xyr[3 * d];
    float dy = xyr[3 * s + 1] - xyr[3 * d + 1];
    float r = sqrtf(dx * dx + dy * dy + 1e-8f);
    const float step = 1.41421356237309515f / 15.f;
    const float gamma = 56.25f;
    float4 o;
    float* op = rbfc + (size_t)p * 16;
#pragma unroll
    for (int q = 0; q < 4; ++q) {
        float d0 = r - (4 * q + 0) * step;
        float d1 = r - (4 * q + 1) * step;
        float d2 = r - (4 * q + 2) * step;
        float d3 = r - (4 * q + 3) * step;
        o.x = __expf(-gamma * d0 * d0);
        o.y = __expf(-gamma * d1 * d1);
        o.z = __expf(-gamma * d2 * d2);
        o.w = __expf(-gamma * d3 * d3);
        *(float4*)(op + 4 * q) = o;
    }
}

// ---- proj: O1||O2 = Abf @ BT^T  (M x 128 @ 128 x 256), fp32 out, no bias ----
__global__ __launch_bounds__(256)
void proj_kernel(const unsigned short* __restrict__ Abf,
                 const unsigned short* __restrict__ BT,   // [256][128] bf16
                 float* __restrict__ O1, float* __restrict__ O2, int M) {
    const int tid = threadIdx.x;
    const int w = tid >> 6, lane = tid & 63;
    const int mr = lane & 15, q = lane >> 4;
    const int row0 = blockIdx.x * 64;
    floatx4 acc[4][4] = {};
#pragma unroll
    for (int kc = 0; kc < 4; ++kc) {
        const int ko = kc * 32 + q * 8;
        shortx8 a[4], b[4];
#pragma unroll
        for (int mt = 0; mt < 4; ++mt) {
            int r = row0 + mt * 16 + mr; if (r >= M) r = M - 1;
            a[mt] = *reinterpret_cast<const shortx8*>(Abf + (size_t)r * DH + ko);
        }
#pragma unroll
        for (int nt = 0; nt < 4; ++nt) {
            int ocol = w * 64 + nt * 16 + mr;
            b[nt] = *reinterpret_cast<const shortx8*>(BT + (size_t)ocol * DH + ko);
        }
#pragma unroll
        for (int mt = 0; mt < 4; ++mt)
#pragma unroll
            for (int nt = 0; nt < 4; ++nt)
                acc[mt][nt] = __builtin_amdgcn_mfma_f32_16x16x32_bf16(a[mt], b[nt], acc[mt][nt], 0, 0, 0);
    }
#pragma unroll
    for (int nt = 0; nt < 4; ++nt) {
        int ocol = w * 64 + nt * 16 + mr;
        float* O = (ocol < DH) ? O1 : O2;
        int col = ocol & (DH - 1);
#pragma unroll
        for (int mt = 0; mt < 4; ++mt)
#pragma unroll
            for (int r4 = 0; r4 < 4; ++r4) {
                int gr = row0 + mt * 16 + q * 4 + r4;
                if (gr < M) O[(size_t)gr * DH + col] = acc[mt][nt][r4];
            }
    }
}

// ---- edge stream + aggregate: one wave per node, float2 channels, packed fp32 ----
__global__ __launch_bounds__(256)
void edge_kernel(const float* __restrict__ Hs, const float* __restrict__ Hd,
                 const float* __restrict__ w1c,   // [16][128] fp32 (pm_w1 rows 256..271)
                 const float* __restrict__ b1,
                 const int* __restrict__ rs, const int* __restrict__ esrc,
                 const float* __restrict__ rbfc,
                 float* __restrict__ S, int N) {
    const int wv = threadIdx.x >> 6;
    const int n = blockIdx.x * 4 + wv;
    if (n >= N) return;
    const int lane = threadIdx.x & 63;
    const int c = lane * 2;
    floatx2 wc[16];
#pragma unroll
    for (int k = 0; k < 16; ++k) wc[k] = *(const floatx2*)(w1c + k * DH + c);
    floatx2 hdn = *(const floatx2*)(Hd + (size_t)n * DH + c) + *(const floatx2*)(b1 + c);
    const int s = rs[n], e = rs[n + 1];
    floatx2 acc = {0.f, 0.f};
#pragma unroll 2
    for (int j = s; j < e; ++j) {
        const int sn = esrc[j];
        floatx2 hs = *(const floatx2*)(Hs + (size_t)sn * DH + c);
        const float* rp = rbfc + (size_t)j * 16;
        floatx2 pre = hs + hdn;
#pragma unroll
        for (int k = 0; k < 16; ++k) pre += rp[k] * wc[k];
        floatx2 sg;
        sg.x = __builtin_amdgcn_rcpf(1.f + __expf(-pre.x));
        sg.y = __builtin_amdgcn_rcpf(1.f + __expf(-pre.y));
        acc += pre * sg;
    }
    *(floatx2*)(S + (size_t)n * DH + c) = acc;
}

// ---- agg = S @ W2 + cnt*b2 (fp32 VALU), out bf16 ----
__global__ __launch_bounds__(128)
void aggw2_kernel(const float* __restrict__ S, const float* __restrict__ W2,
                  const float* __restrict__ b2, const float* __restrict__ cntf,
                  unsigned short* __restrict__ aggbf, int N) {
    __shared__ float Ssh[16][DH];
    int n0 = blockIdx.x * 16, c = threadIdx.x;
    for (int i = c; i < 16 * DH; i += 128) {
        int r = i >> 7, k = i & 127;
        int n = n0 + r;
        Ssh[r][k] = (n < N) ? S[(size_t)n * DH + k] : 0.f;
    }
    __syncthreads();
    float acc[16];
#pragma unroll
    for (int r = 0; r < 16; ++r) acc[r] = 0.f;
    for (int k = 0; k < DH; ++k) {
        float wv = W2[(size_t)k * DH + c];
#pragma unroll
        for (int r = 0; r < 16; ++r) acc[r] += Ssh[r][k] * wv;
    }
    float b2c = b2[c];
#pragma unroll
    for (int r = 0; r < 16; ++r) {
        int n = n0 + r;
        if (n < N) aggbf[(size_t)n * DH + c] = f2bf(acc[r] + cntf[n] * b2c);
    }
}

// ---- node update: h_up = mlp2([h|agg]) ; h = LN(h + h_up) ; fused ----
__global__ __launch_bounds__(256)
void upd_kernel(unsigned short* hbf,
                const unsigned short* __restrict__ aggbf,
                float* h,
                const unsigned short* __restrict__ P1T,    // [128][256]
                const float* __restrict__ b1v,
                const unsigned short* __restrict__ P2T,    // [128][128]
                const float* __restrict__ b2v,
                const float* __restrict__ g, const float* __restrict__ bb,
                int M) {
    __shared__ unsigned short HID[64 * 136];
    __shared__ float red[4][64][2];
    __shared__ float stats[64][2];
    const int tid = threadIdx.x;
    const int w = tid >> 6, lane = tid & 63;
    const int mr = lane & 15, q = lane >> 4;
    const int row0 = blockIdx.x * 64;

    floatx4 acc[4][2] = {};
#pragma unroll
    for (int kc = 0; kc < 8; ++kc) {
        const int ko = kc * 32 + q * 8;
        shortx8 a[4], bfr[2];
#pragma unroll
        for (int mt = 0; mt < 4; ++mt) {
            int r = row0 + mt * 16 + mr; if (r >= M) r = M - 1;
            const unsigned short* sp = (ko < DH) ? (hbf + (size_t)r * DH + ko)
                                                 : (aggbf + (size_t)r * DH + (ko - DH));
            a[mt] = *reinterpret_cast<const shortx8*>(sp);
        }
#pragma unroll
        for (int nt = 0; nt < 2; ++nt)
            bfr[nt] = *reinterpret_cast<const shortx8*>(P1T + (size_t)(w * 32 + nt * 16 + mr) * 256 + ko);
#pragma unroll
        for (int mt = 0; mt < 4; ++mt)
#pragma unroll
            for (int nt = 0; nt < 2; ++nt)
                acc[mt][nt] = __builtin_amdgcn_mfma_f32_16x16x32_bf16(a[mt], bfr[nt], acc[mt][nt], 0, 0, 0);
    }
#pragma unroll
    for (int nt = 0; nt < 2; ++nt) {
        int col = w * 32 + nt * 16 + mr;
        float bv = b1v[col];
#pragma unroll
        for (int mt = 0; mt < 4; ++mt)
#pragma unroll
            for (int r4 = 0; r4 < 4; ++r4) {
                int row = mt * 16 + q * 4 + r4;
                HID[row * 136 + col] = f2bf(fast_silu(acc[mt][nt][r4] + bv));
            }
    }
    __syncthreads();

    floatx4 acc3[4][2] = {};
#pragma unroll
    for (int kc = 0; kc < 4; ++kc) {
        const int ko = kc * 32 + q * 8;
        shortx8 a[4], bfr[2];
#pragma unroll
        for (int mt = 0; mt < 4; ++mt)
            a[mt] = *reinterpret_cast<const shortx8*>(HID + (mt * 16 + mr) * 136 + ko);
#pragma unroll
        for (int nt = 0; nt < 2; ++nt)
            bfr[nt] = *reinterpret_cast<const shortx8*>(P2T + (size_t)(w * 32 + nt * 16 + mr) * DH + ko);
#pragma unroll
        for (int mt = 0; mt < 4; ++mt)
#pragma unroll
            for (int nt = 0; nt < 2; ++nt)
                acc3[mt][nt] = __builtin_amdgcn_mfma_f32_16x16x32_bf16(a[mt], bfr[nt], acc3[mt][nt], 0, 0, 0);
    }
#pragma unroll
    for (int nt = 0; nt < 2; ++nt) {
        int col = w * 32 + nt * 16 + mr;
        float b2c = b2v[col];
#pragma unroll
        for (int mt = 0; mt < 4; ++mt)
#pragma unroll
            for (int r4 = 0; r4 < 4; ++r4) {
                int gr = row0 + mt * 16 + q * 4 + r4;
                float hv = (gr < M) ? h[(size_t)gr * DH + col] : 0.f;
                acc3[mt][nt][r4] = acc3[mt][nt][r4] + b2c + hv;
            }
    }
#pragma unroll
    for (int mt = 0; mt < 4; ++mt)
#pragma unroll
        for (int r4 = 0; r4 < 4; ++r4) {
            float y0 = acc3[mt][0][r4], y1 = acc3[mt][1][r4];
            float s1 = y0 + y1, s2 = y0 * y0 + y1 * y1;
#pragma unroll
            for (int m = 1; m < 16; m <<= 1) {
                s1 += __shfl_xor(s1, m);
                s2 += __shfl_xor(s2, m);
            }
            if (mr == 0) {
                int row = mt * 16 + q * 4 + r4;
                red[w][row][0] = s1; red[w][row][1] = s2;
            }
        }
    __syncthreads();
    if (tid < 64) {
        float s1 = red[0][tid][0] + red[1][tid][0] + red[2][tid][0] + red[3][tid][0];
        float s2 = red[0][tid][1] + red[1][tid][1] + red[2][tid][1] + red[3][tid][1];
        float mu = s1 * (1.f / DH);
        float var = s2 * (1.f / DH) - mu * mu;
        stats[tid][0] = mu;
        stats[tid][1] = rsqrtf(var + 1e-5f);
    }
    __syncthreads();
#pragma unroll
    for (int nt = 0; nt < 2; ++nt) {
        int col = w * 32 + nt * 16 + mr;
        float gc = g[col], bc = bb[col];
#pragma unroll
        for (int mt = 0; mt < 4; ++mt)
#pragma unroll
            for (int r4 = 0; r4 < 4; ++r4) {
                int row = mt * 16 + q * 4 + r4;
                int gr = row0 + row;
                if (gr < M) {
                    float yv = (acc3[mt][nt][r4] - stats[row][0]) * stats[row][1] * gc + bc;
                    h[(size_t)gr * DH + col] = yv;
                    hbf[(size_t)gr * DH + col] = f2bf(yv);
                }
            }
    }
}

// ---- pair head: one wave per pair ----
__global__ __launch_bounds__(256)
void pair_kernel(const float* __restrict__ Hu, const float* __restrict__ Hv,
                 const int* __restrict__ pairs, const float* __restrict__ xyr,
                 const float* __restrict__ ehw1c,   // [4][128] fp32
                 const float* __restrict__ eb1, const float* __restrict__ ew2,
                 const float* __restrict__ eb2,
                 float* __restrict__ out, int P) {
    int w = threadIdx.x >> 6, lane = threadIdx.x & 63;
    int p = blockIdx.x * 4 + w;
    if (p >= P) return;
    int u = pairs[2 * p], v = pairs[2 * p + 1];
    float ru = xyr[3 * u + 2], rv = xyr[3 * v + 2];
    float dx = xyr[3 * u] - xyr[3 * v];
    float dy = xyr[3 * u + 1] - xyr[3 * v + 1];
    float dist = sqrtf(dx * dx + dy * dy + 1e-8f);
    float adr = fabsf(ru - rv);
    int c = lane * 2;
    float2 hu = *(const float2*)(Hu + (size_t)u * DH + c);
    float2 hv = *(const float2*)(Hv + (size_t)v * DH + c);
    float2 bv = *(const float2*)(eb1 + c);
    float2 wv = *(const float2*)(ew2 + c);
    float2 c0 = *(const float2*)(ehw1c + 0 * DH + c);
    float2 c1 = *(const float2*)(ehw1c + 1 * DH + c);
    float2 c2 = *(const float2*)(ehw1c + 2 * DH + c);
    float2 c3 = *(const float2*)(ehw1c + 3 * DH + c);
    float px = hu.x + hv.x + bv.x + ru * c0.x + rv * c1.x + dist * c2.x + adr * c3.x;
    float py = hu.y + hv.y + bv.y + ru * c0.y + rv * c1.y + dist * c2.y + adr * c3.y;
    float val = fast_silu(px) * wv.x + fast_silu(py) * wv.y;
#pragma unroll
    for (int m = 1; m < 64; m <<= 1) val += __shfl_xor(val, m);
    if (lane == 0) out[p] = val + eb2[0];
}

extern "C" void kernel_launch(void* const* d_in, const int* in_sizes, int n_in,
                              void* d_out, int out_size, void* d_ws, size_t ws_size,
                              hipStream_t stream) {
    const float* xyr     = (const float*)d_in[0];
    const int*   eidx    = (const int*)d_in[1];
    const int*   pairs   = (const int*)d_in[2];
    const float* node_w1 = (const float*)d_in[3];
    const float* node_b1 = (const float*)d_in[4];
    const float* node_w2 = (const float*)d_in[5];
    const float* node_b2 = (const float*)d_in[6];
    const float* pm_w1   = (const float*)d_in[7];
    const float* pm_b1   = (const float*)d_in[8];
    const float* pm_w2   = (const float*)d_in[9];
    const float* pm_b2   = (const float*)d_in[10];
    const float* ph_w1   = (const float*)d_in[11];
    const float* ph_b1   = (const float*)d_in[12];
    const float* ph_w2   = (const float*)d_in[13];
    const float* ph_b2   = (const float*)d_in[14];
    const float* ln_g    = (const float*)d_in[15];
    const float* ln_b    = (const float*)d_in[16];
    const float* eh_w1   = (const float*)d_in[17];
    const float* eh_b1   = (const float*)d_in[18];
    const float* eh_w2   = (const float*)d_in[19];
    const float* eh_b2   = (const float*)d_in[20];

    const int N = in_sizes[0] / 3;
    const int E = in_sizes[1] / 2;
    const int P = in_sizes[2] / 2;
    const int* src = eidx;
    const int* dst = eidx + E;

    char* ws = (char*)d_ws;
    size_t off = 0;
    auto alloc = [&](size_t bytes) -> char* {
        char* p = ws + off;
        off += (bytes + 255) & ~(size_t)255;
        return p;
    };
    unsigned short* W1abT = (unsigned short*)alloc((size_t)3 * 256 * 128 * 2);
    unsigned short* PH1T  = (unsigned short*)alloc((size_t)3 * 128 * 256 * 2);
    unsigned short* PH2T  = (unsigned short*)alloc((size_t)3 * 128 * 128 * 2);
    unsigned short* EHT   = (unsigned short*)alloc((size_t)256 * 128 * 2);
    float*          h     = (float*)alloc((size_t)N * DH * 4);
    unsigned short* hbf   = (unsigned short*)alloc((size_t)N * DH * 2);
    float*          Hs    = (float*)alloc((size_t)N * DH * 4);
    float*          Hd    = (float*)alloc((size_t)N * DH * 4);
    float*          S     = (float*)alloc((size_t)N * DH * 4);
    unsigned short* aggbf = (unsigned short*)alloc((size_t)N * DH * 2);
    float*          rbfc  = (float*)alloc((size_t)E * 16 * 4);
    int*            esrc  = (int*)alloc((size_t)E * 4);
    int*            cnt   = (int*)alloc((size_t)N * 4);
    int*            rs    = (int*)alloc((size_t)(N + 1) * 4);
    int*            cursor= (int*)alloc((size_t)N * 4);
    float*          cntf  = (float*)alloc((size_t)N * 4);
    (void)ws_size; (void)n_in; (void)out_size;

    prep_split_kernel<<<(3 * 256 * 128 + 255) / 256, 256, 0, stream>>>(pm_w1, W1abT, 3, 272);
    prep_split_kernel<<<(256 * 128 + 255) / 256, 256, 0, stream>>>(eh_w1, EHT, 1, 260);
    prep_T_kernel<<<(3 * 128 * 256 + 255) / 256, 256, 0, stream>>>(ph_w1, PH1T, 3, 256);
    prep_T_kernel<<<(3 * 128 * 128 + 255) / 256, 256, 0, stream>>>(ph_w2, PH2T, 3, 128);

    node_enc_kernel<<<(N + 15) / 16, 128, 0, stream>>>(xyr, node_w1, node_b1, node_w2, node_b2, h, hbf, N);
    hipMemsetAsync(cnt, 0, (size_t)N * 4, stream);
    count_kernel<<<(E + 255) / 256, 256, 0, stream>>>(dst, cnt, E);
    scan_kernel<<<1, 1024, 0, stream>>>(cnt, rs, cursor, cntf, N);
    fill_kernel<<<(E + 255) / 256, 256, 0, stream>>>(src, dst, cursor, xyr, esrc, rbfc, E);

    const int MB = (N + 63) / 64;
    for (int l = 0; l < 3; ++l) {
        proj_kernel<<<MB, 256, 0, stream>>>(hbf, W1abT + (size_t)l * 256 * 128, Hs, Hd, N);
        edge_kernel<<<(N + 3) / 4, 256, 0, stream>>>(Hs, Hd, pm_w1 + (size_t)l * 272 * 128 + 256 * 128,
                                                     pm_b1 + l * DH, rs, esrc, rbfc, S, N);
        aggw2_kernel<<<(N + 15) / 16, 128, 0, stream>>>(S, pm_w2 + (size_t)l * 128 * 128,
                                                        pm_b2 + l * DH, cntf, aggbf, N);
        upd_kernel<<<MB, 256, 0, stream>>>(hbf, aggbf, h,
                                           PH1T + (size_t)l * 128 * 256, ph_b1 + l * DH,
                                           PH2T + (size_t)l * 128 * 128, ph_b2 + l * DH,
                                           ln_g + l * DH, ln_b + l * DH, N);
    }

    proj_kernel<<<MB, 256, 0, stream>>>(hbf, EHT, Hs, Hd, N);
    pair_kernel<<<(P + 3) / 4, 256, 0, stream>>>(Hs, Hd, pairs, xyr, eh_w1 + 256 * DH,
                                                 eh_b1, eh_w2, eh_b2, (float*)d_out, P);
}

// Round 4
// 611.765 us; speedup vs baseline: 1.0136x; 1.0136x over previous
//
#include <hip/hip_runtime.h>

#define DH 128

typedef float  floatx4 __attribute__((ext_vector_type(4)));
typedef float  floatx2 __attribute__((ext_vector_type(2)));
typedef short  shortx8 __attribute__((ext_vector_type(8)));

__device__ __forceinline__ unsigned short f2bf(float f) {
    unsigned u = __builtin_bit_cast(unsigned, f);
    u += 0x7fffu + ((u >> 16) & 1u);
    return (unsigned short)(u >> 16);
}
__device__ __forceinline__ float fast_silu(float x) {
    return x * __builtin_amdgcn_rcpf(1.f + __expf(-x));
}

// ---- one prep kernel for all four weight transposes ----
// split: dst[l][j][k] = src[l][(j>>7)*128+k][j&127]  (j<256,k<128)
// plainT: dst[l][j][k] = src[l][k][j]                (j<128,k<K)
__global__ void prep_all_kernel(const float* __restrict__ pm_w1, const float* __restrict__ eh_w1,
                                const float* __restrict__ ph_w1, const float* __restrict__ ph_w2,
                                unsigned short* __restrict__ W1abT, unsigned short* __restrict__ EHT,
                                unsigned short* __restrict__ PH1T, unsigned short* __restrict__ PH2T) {
    int idx = blockIdx.x * 256 + threadIdx.x;
    const int nA = 3 * 256 * 128;          // W1abT from pm_w1 (SR=272)
    const int nB = 256 * 128;              // EHT from eh_w1 (SR=260)
    const int nC = 3 * 128 * 256;          // PH1T from ph_w1 (K=256)
    const int nD = 3 * 128 * 128;          // PH2T from ph_w2 (K=128)
    if (idx < nA) {
        int l = idx / (256 * 128);
        int rem = idx - l * 256 * 128;
        int j = rem >> 7, k = rem & 127;
        int srow = ((j >> 7) << 7) + k;
        W1abT[idx] = f2bf(pm_w1[(size_t)l * 272 * 128 + (size_t)srow * 128 + (j & 127)]);
        return;
    }
    idx -= nA;
    if (idx < nB) {
        int j = idx >> 7, k = idx & 127;
        int srow = ((j >> 7) << 7) + k;
        EHT[idx] = f2bf(eh_w1[(size_t)srow * 128 + (j & 127)]);
        return;
    }
    idx -= nB;
    if (idx < nC) {
        int l = idx / (128 * 256);
        int rem = idx - l * 128 * 256;
        int j = rem >> 8, k = rem & 255;
        PH1T[idx] = f2bf(ph_w1[(size_t)l * 256 * 128 + (size_t)k * 128 + j]);
        return;
    }
    idx -= nC;
    if (idx < nD) {
        int l = idx / (128 * 128);
        int rem = idx - l * 128 * 128;
        int j = rem >> 7, k = rem & 127;
        PH2T[idx] = f2bf(ph_w2[(size_t)l * 128 * 128 + (size_t)k * 128 + j]);
    }
}

// ---- node encoder: h = silu(x@w1+b1)@w2+b2 ----
__global__ __launch_bounds__(128)
void node_enc_kernel(const float* __restrict__ xyr,
                     const float* __restrict__ w1, const float* __restrict__ b1,
                     const float* __restrict__ w2, const float* __restrict__ b2,
                     float* __restrict__ h, unsigned short* __restrict__ hbf, int N) {
    __shared__ float xs[16][3];
    __shared__ float hid[16][DH];
    int n0 = blockIdx.x * 16;
    int t = threadIdx.x;
    if (t < 48) {
        int i = t / 3, j = t - 3 * (t / 3);
        int n = n0 + i; if (n >= N) n = N - 1;
        xs[i][j] = xyr[3 * n + j];
    }
    __syncthreads();
    int col = t;
    float w10 = w1[col], w11 = w1[DH + col], w12 = w1[2 * DH + col];
    float bb = b1[col];
#pragma unroll
    for (int i = 0; i < 16; ++i) {
        float v = bb + xs[i][0] * w10 + xs[i][1] * w11 + xs[i][2] * w12;
        hid[i][col] = fast_silu(v);
    }
    __syncthreads();
    float a[16];
#pragma unroll
    for (int i = 0; i < 16; ++i) a[i] = b2[col];
    for (int j = 0; j < DH; ++j) {
        float wv = w2[j * DH + col];
#pragma unroll
        for (int i = 0; i < 16; ++i) a[i] += hid[i][j] * wv;
    }
    for (int i = 0; i < 16; ++i) {
        int n = n0 + i;
        if (n < N) {
            h[(size_t)n * DH + col] = a[i];
            hbf[(size_t)n * DH + col] = f2bf(a[i]);
        }
    }
}

// ---- CSR build ----
__global__ void count_kernel(const int* __restrict__ dst, int* __restrict__ cnt, int E) {
    int e = blockIdx.x * 256 + threadIdx.x;
    if (e < E) atomicAdd(&cnt[dst[e]], 1);
}
__global__ __launch_bounds__(1024)
void scan_kernel(const int* __restrict__ cnt, int* __restrict__ rs, int* __restrict__ cursor,
                 float* __restrict__ cntf, int N) {
    __shared__ int ps[1024];
    const int CH = 16;
    int t = threadIdx.x;
    int base = t * CH;
    int loc[CH];
    int s = 0;
#pragma unroll
    for (int j = 0; j < CH; ++j) {
        int i = base + j;
        int v = (i < N) ? cnt[i] : 0;
        if (i < N) cntf[i] = (float)v;
        loc[j] = s; s += v;
    }
    ps[t] = s;
    __syncthreads();
    for (int off = 1; off < 1024; off <<= 1) {
        int v = (t >= off) ? ps[t - off] : 0;
        __syncthreads();
        ps[t] += v;
        __syncthreads();
    }
    int pre = (t > 0) ? ps[t - 1] : 0;
#pragma unroll
    for (int j = 0; j < CH; ++j) {
        int i = base + j;
        if (i < N) { int v = pre + loc[j]; rs[i] = v; cursor[i] = v; }
    }
    if (t == 0) rs[N] = ps[1023];
}
// ---- fill + edge prep fused ----
__global__ void fill_kernel(const int* __restrict__ src, const int* __restrict__ dst,
                            int* __restrict__ cursor, const float* __restrict__ xyr,
                            int* __restrict__ esrc, float* __restrict__ rbfc, int E) {
    int e = blockIdx.x * 256 + threadIdx.x;
    if (e >= E) return;
    int s = src[e], d = dst[e];
    int p = atomicAdd(&cursor[d], 1);
    esrc[p] = s;
    float dx = xyr[3 * s] - xyr[3 * d];
    float dy = xyr[3 * s + 1] - xyr[3 * d + 1];
    float r = sqrtf(dx * dx + dy * dy + 1e-8f);
    const float step = 1.41421356237309515f / 15.f;
    const float gamma = 56.25f;
    float4 o;
    float* op = rbfc + (size_t)p * 16;
#pragma unroll
    for (int q = 0; q < 4; ++q) {
        float d0 = r - (4 * q + 0) * step;
        float d1 = r - (4 * q + 1) * step;
        float d2 = r - (4 * q + 2) * step;
        float d3 = r - (4 * q + 3) * step;
        o.x = __expf(-gamma * d0 * d0);
        o.y = __expf(-gamma * d1 * d1);
        o.z = __expf(-gamma * d2 * d2);
        o.w = __expf(-gamma * d3 * d3);
        *(float4*)(op + 4 * q) = o;
    }
}

// ---- proj: O1||O2 = Abf @ BT^T  (M x 128 @ 128 x 256), fp32 out ----
__global__ __launch_bounds__(256)
void proj_kernel(const unsigned short* __restrict__ Abf,
                 const unsigned short* __restrict__ BT,   // [256][128] bf16
                 float* __restrict__ O1, float* __restrict__ O2, int M) {
    const int tid = threadIdx.x;
    const int w = tid >> 6, lane = tid & 63;
    const int mr = lane & 15, q = lane >> 4;
    const int row0 = blockIdx.x * 64;
    floatx4 acc[4][4] = {};
#pragma unroll
    for (int kc = 0; kc < 4; ++kc) {
        const int ko = kc * 32 + q * 8;
        shortx8 a[4], b[4];
#pragma unroll
        for (int mt = 0; mt < 4; ++mt) {
            int r = row0 + mt * 16 + mr; if (r >= M) r = M - 1;
            a[mt] = *reinterpret_cast<const shortx8*>(Abf + (size_t)r * DH + ko);
        }
#pragma unroll
        for (int nt = 0; nt < 4; ++nt) {
            int ocol = w * 64 + nt * 16 + mr;
            b[nt] = *reinterpret_cast<const shortx8*>(BT + (size_t)ocol * DH + ko);
        }
#pragma unroll
        for (int mt = 0; mt < 4; ++mt)
#pragma unroll
            for (int nt = 0; nt < 4; ++nt)
                acc[mt][nt] = __builtin_amdgcn_mfma_f32_16x16x32_bf16(a[mt], b[nt], acc[mt][nt], 0, 0, 0);
    }
#pragma unroll
    for (int nt = 0; nt < 4; ++nt) {
        int ocol = w * 64 + nt * 16 + mr;
        float* O = (ocol < DH) ? O1 : O2;
        int col = ocol & (DH - 1);
#pragma unroll
        for (int mt = 0; mt < 4; ++mt)
#pragma unroll
            for (int r4 = 0; r4 < 4; ++r4) {
                int gr = row0 + mt * 16 + q * 4 + r4;
                if (gr < M) O[(size_t)gr * DH + col] = acc[mt][nt][r4];
            }
    }
}

// ---- edge stream + aggregate: one wave per node, float2 channels,
//      rbf via float4 broadcast loads, 1-deep esrc->Hs prefetch pipeline ----
__global__ __launch_bounds__(256)
void edge_kernel(const float* __restrict__ Hs, const float* __restrict__ Hd,
                 const float* __restrict__ w1c,   // [16][128] fp32 (pm_w1 rows 256..271)
                 const float* __restrict__ b1,
                 const int* __restrict__ rs, const int* __restrict__ esrc,
                 const float* __restrict__ rbfc,
                 float* __restrict__ S, int N) {
    const int wv = threadIdx.x >> 6;
    const int n = blockIdx.x * 4 + wv;
    if (n >= N) return;
    const int lane = threadIdx.x & 63;
    const int c = lane * 2;
    floatx2 wc[16];
#pragma unroll
    for (int k = 0; k < 16; ++k) wc[k] = *(const floatx2*)(w1c + k * DH + c);
    floatx2 hdn = *(const floatx2*)(Hd + (size_t)n * DH + c) + *(const floatx2*)(b1 + c);
    const int s = rs[n], e = rs[n + 1];
    floatx2 acc = {0.f, 0.f};
    if (s < e) {
        int sn0 = esrc[s];
        floatx2 hs = *(const floatx2*)(Hs + (size_t)sn0 * DH + c);
        for (int j = s; j < e; ++j) {
            floatx2 hs_cur = hs;
            int jn = (j + 1 < e) ? (j + 1) : j;          // branchless prefetch clamp
            int sn = esrc[jn];
            hs = *(const floatx2*)(Hs + (size_t)sn * DH + c);
            const float4* rp = (const float4*)(rbfc + (size_t)j * 16);
            float4 r0 = rp[0], r1 = rp[1], r2 = rp[2], r3 = rp[3];
            floatx2 pre = hs_cur + hdn;
            pre += r0.x * wc[0];  pre += r0.y * wc[1];  pre += r0.z * wc[2];  pre += r0.w * wc[3];
            pre += r1.x * wc[4];  pre += r1.y * wc[5];  pre += r1.z * wc[6];  pre += r1.w * wc[7];
            pre += r2.x * wc[8];  pre += r2.y * wc[9];  pre += r2.z * wc[10]; pre += r2.w * wc[11];
            pre += r3.x * wc[12]; pre += r3.y * wc[13]; pre += r3.z * wc[14]; pre += r3.w * wc[15];
            floatx2 sg;
            sg.x = __builtin_amdgcn_rcpf(1.f + __expf(-pre.x));
            sg.y = __builtin_amdgcn_rcpf(1.f + __expf(-pre.y));
            acc += pre * sg;
        }
    }
    *(floatx2*)(S + (size_t)n * DH + c) = acc;
}

// ---- agg = S @ W2 + cnt*b2 (fp32 VALU), out bf16 ----
__global__ __launch_bounds__(128)
void aggw2_kernel(const float* __restrict__ S, const float* __restrict__ W2,
                  const float* __restrict__ b2, const float* __restrict__ cntf,
                  unsigned short* __restrict__ aggbf, int N) {
    __shared__ float Ssh[16][DH];
    int n0 = blockIdx.x * 16, c = threadIdx.x;
    for (int i = c; i < 16 * DH; i += 128) {
        int r = i >> 7, k = i & 127;
        int n = n0 + r;
        Ssh[r][k] = (n < N) ? S[(size_t)n * DH + k] : 0.f;
    }
    __syncthreads();
    float acc[16];
#pragma unroll
    for (int r = 0; r < 16; ++r) acc[r] = 0.f;
    for (int k = 0; k < DH; ++k) {
        float wv = W2[(size_t)k * DH + c];
#pragma unroll
        for (int r = 0; r < 16; ++r) acc[r] += Ssh[r][k] * wv;
    }
    float b2c = b2[c];
#pragma unroll
    for (int r = 0; r < 16; ++r) {
        int n = n0 + r;
        if (n < N) aggbf[(size_t)n * DH + c] = f2bf(acc[r] + cntf[n] * b2c);
    }
}

// ---- node update: h_up = mlp2([h|agg]) ; h = LN(h + h_up) ; fused ----
__global__ __launch_bounds__(256)
void upd_kernel(unsigned short* hbf,
                const unsigned short* __restrict__ aggbf,
                float* h,
                const unsigned short* __restrict__ P1T,    // [128][256]
                const float* __restrict__ b1v,
                const unsigned short* __restrict__ P2T,    // [128][128]
                const float* __restrict__ b2v,
                const float* __restrict__ g, const float* __restrict__ bb,
                int M) {
    __shared__ unsigned short HID[64 * 136];
    __shared__ float red[4][64][2];
    __shared__ float stats[64][2];
    const int tid = threadIdx.x;
    const int w = tid >> 6, lane = tid & 63;
    const int mr = lane & 15, q = lane >> 4;
    const int row0 = blockIdx.x * 64;

    floatx4 acc[4][2] = {};
#pragma unroll
    for (int kc = 0; kc < 8; ++kc) {
        const int ko = kc * 32 + q * 8;
        shortx8 a[4], bfr[2];
#pragma unroll
        for (int mt = 0; mt < 4; ++mt) {
            int r = row0 + mt * 16 + mr; if (r >= M) r = M - 1;
            const unsigned short* sp = (ko < DH) ? (hbf + (size_t)r * DH + ko)
                                                 : (aggbf + (size_t)r * DH + (ko - DH));
            a[mt] = *reinterpret_cast<const shortx8*>(sp);
        }
#pragma unroll
        for (int nt = 0; nt < 2; ++nt)
            bfr[nt] = *reinterpret_cast<const shortx8*>(P1T + (size_t)(w * 32 + nt * 16 + mr) * 256 + ko);
#pragma unroll
        for (int mt = 0; mt < 4; ++mt)
#pragma unroll
            for (int nt = 0; nt < 2; ++nt)
                acc[mt][nt] = __builtin_amdgcn_mfma_f32_16x16x32_bf16(a[mt], bfr[nt], acc[mt][nt], 0, 0, 0);
    }
#pragma unroll
    for (int nt = 0; nt < 2; ++nt) {
        int col = w * 32 + nt * 16 + mr;
        float bv = b1v[col];
#pragma unroll
        for (int mt = 0; mt < 4; ++mt)
#pragma unroll
            for (int r4 = 0; r4 < 4; ++r4) {
                int row = mt * 16 + q * 4 + r4;
                HID[row * 136 + col] = f2bf(fast_silu(acc[mt][nt][r4] + bv));
            }
    }
    __syncthreads();

    floatx4 acc3[4][2] = {};
#pragma unroll
    for (int kc = 0; kc < 4; ++kc) {
        const int ko = kc * 32 + q * 8;
        shortx8 a[4], bfr[2];
#pragma unroll
        for (int mt = 0; mt < 4; ++mt)
            a[mt] = *reinterpret_cast<const shortx8*>(HID + (mt * 16 + mr) * 136 + ko);
#pragma unroll
        for (int nt = 0; nt < 2; ++nt)
            bfr[nt] = *reinterpret_cast<const shortx8*>(P2T + (size_t)(w * 32 + nt * 16 + mr) * DH + ko);
#pragma unroll
        for (int mt = 0; mt < 4; ++mt)
#pragma unroll
            for (int nt = 0; nt < 2; ++nt)
                acc3[mt][nt] = __builtin_amdgcn_mfma_f32_16x16x32_bf16(a[mt], bfr[nt], acc3[mt][nt], 0, 0, 0);
    }
#pragma unroll
    for (int nt = 0; nt < 2; ++nt) {
        int col = w * 32 + nt * 16 + mr;
        float b2c = b2v[col];
#pragma unroll
        for (int mt = 0; mt < 4; ++mt)
#pragma unroll
            for (int r4 = 0; r4 < 4; ++r4) {
                int gr = row0 + mt * 16 + q * 4 + r4;
                float hv = (gr < M) ? h[(size_t)gr * DH + col] : 0.f;
                acc3[mt][nt][r4] = acc3[mt][nt][r4] + b2c + hv;
            }
    }
#pragma unroll
    for (int mt = 0; mt < 4; ++mt)
#pragma unroll
        for (int r4 = 0; r4 < 4; ++r4) {
            float y0 = acc3[mt][0][r4], y1 = acc3[mt][1][r4];
            float s1 = y0 + y1, s2 = y0 * y0 + y1 * y1;
#pragma unroll
            for (int m = 1; m < 16; m <<= 1) {
                s1 += __shfl_xor(s1, m);
                s2 += __shfl_xor(s2, m);
            }
            if (mr == 0) {
                int row = mt * 16 + q * 4 + r4;
                red[w][row][0] = s1; red[w][row][1] = s2;
            }
        }
    __syncthreads();
    if (tid < 64) {
        float s1 = red[0][tid][0] + red[1][tid][0] + red[2][tid][0] + red[3][tid][0];
        float s2 = red[0][tid][1] + red[1][tid][1] + red[2][tid][1] + red[3][tid][1];
        float mu = s1 * (1.f / DH);
        float var = s2 * (1.f / DH) - mu * mu;
        stats[tid][0] = mu;
        stats[tid][1] = rsqrtf(var + 1e-5f);
    }
    __syncthreads();
#pragma unroll
    for (int nt = 0; nt < 2; ++nt) {
        int col = w * 32 + nt * 16 + mr;
        float gc = g[col], bc = bb[col];
#pragma unroll
        for (int mt = 0; mt < 4; ++mt)
#pragma unroll
            for (int r4 = 0; r4 < 4; ++r4) {
                int row = mt * 16 + q * 4 + r4;
                int gr = row0 + row;
                if (gr < M) {
                    float yv = (acc3[mt][nt][r4] - stats[row][0]) * stats[row][1] * gc + bc;
                    h[(size_t)gr * DH + col] = yv;
                    hbf[(size_t)gr * DH + col] = f2bf(yv);
                }
            }
    }
}

// ---- pair head: one wave per pair ----
__global__ __launch_bounds__(256)
void pair_kernel(const float* __restrict__ Hu, const float* __restrict__ Hv,
                 const int* __restrict__ pairs, const float* __restrict__ xyr,
                 const float* __restrict__ ehw1c,   // [4][128] fp32
                 const float* __restrict__ eb1, const float* __restrict__ ew2,
                 const float* __restrict__ eb2,
                 float* __restrict__ out, int P) {
    int w = threadIdx.x >> 6, lane = threadIdx.x & 63;
    int p = blockIdx.x * 4 + w;
    if (p >= P) return;
    int u = pairs[2 * p], v = pairs[2 * p + 1];
    float ru = xyr[3 * u + 2], rv = xyr[3 * v + 2];
    float dx = xyr[3 * u] - xyr[3 * v];
    float dy = xyr[3 * u + 1] - xyr[3 * v + 1];
    float dist = sqrtf(dx * dx + dy * dy + 1e-8f);
    float adr = fabsf(ru - rv);
    int c = lane * 2;
    float2 hu = *(const float2*)(Hu + (size_t)u * DH + c);
    float2 hv = *(const float2*)(Hv + (size_t)v * DH + c);
    float2 bv = *(const float2*)(eb1 + c);
    float2 wv = *(const float2*)(ew2 + c);
    float2 c0 = *(const float2*)(ehw1c + 0 * DH + c);
    float2 c1 = *(const float2*)(ehw1c + 1 * DH + c);
    float2 c2 = *(const float2*)(ehw1c + 2 * DH + c);
    float2 c3 = *(const float2*)(ehw1c + 3 * DH + c);
    float px = hu.x + hv.x + bv.x + ru * c0.x + rv * c1.x + dist * c2.x + adr * c3.x;
    float py = hu.y + hv.y + bv.y + ru * c0.y + rv * c1.y + dist * c2.y + adr * c3.y;
    float val = fast_silu(px) * wv.x + fast_silu(py) * wv.y;
#pragma unroll
    for (int m = 1; m < 64; m <<= 1) val += __shfl_xor(val, m);
    if (lane == 0) out[p] = val + eb2[0];
}

extern "C" void kernel_launch(void* const* d_in, const int* in_sizes, int n_in,
                              void* d_out, int out_size, void* d_ws, size_t ws_size,
                              hipStream_t stream) {
    const float* xyr     = (const float*)d_in[0];
    const int*   eidx    = (const int*)d_in[1];
    const int*   pairs   = (const int*)d_in[2];
    const float* node_w1 = (const float*)d_in[3];
    const float* node_b1 = (const float*)d_in[4];
    const float* node_w2 = (const float*)d_in[5];
    const float* node_b2 = (const float*)d_in[6];
    const float* pm_w1   = (const float*)d_in[7];
    const float* pm_b1   = (const float*)d_in[8];
    const float* pm_w2   = (const float*)d_in[9];
    const float* pm_b2   = (const float*)d_in[10];
    const float* ph_w1   = (const float*)d_in[11];
    const float* ph_b1   = (const float*)d_in[12];
    const float* ph_w2   = (const float*)d_in[13];
    const float* ph_b2   = (const float*)d_in[14];
    const float* ln_g    = (const float*)d_in[15];
    const float* ln_b    = (const float*)d_in[16];
    const float* eh_w1   = (const float*)d_in[17];
    const float* eh_b1   = (const float*)d_in[18];
    const float* eh_w2   = (const float*)d_in[19];
    const float* eh_b2   = (const float*)d_in[20];

    const int N = in_sizes[0] / 3;
    const int E = in_sizes[1] / 2;
    const int P = in_sizes[2] / 2;
    const int* src = eidx;
    const int* dst = eidx + E;

    char* ws = (char*)d_ws;
    size_t off = 0;
    auto alloc = [&](size_t bytes) -> char* {
        char* p = ws + off;
        off += (bytes + 255) & ~(size_t)255;
        return p;
    };
    unsigned short* W1abT = (unsigned short*)alloc((size_t)3 * 256 * 128 * 2);
    unsigned short* PH1T  = (unsigned short*)alloc((size_t)3 * 128 * 256 * 2);
    unsigned short* PH2T  = (unsigned short*)alloc((size_t)3 * 128 * 128 * 2);
    unsigned short* EHT   = (unsigned short*)alloc((size_t)256 * 128 * 2);
    float*          h     = (float*)alloc((size_t)N * DH * 4);
    unsigned short* hbf   = (unsigned short*)alloc((size_t)N * DH * 2);
    float*          Hs    = (float*)alloc((size_t)N * DH * 4);
    float*          Hd    = (float*)alloc((size_t)N * DH * 4);
    float*          S     = (float*)alloc((size_t)N * DH * 4);
    unsigned short* aggbf = (unsigned short*)alloc((size_t)N * DH * 2);
    float*          rbfc  = (float*)alloc((size_t)E * 16 * 4);
    int*            esrc  = (int*)alloc((size_t)E * 4);
    int*            cnt   = (int*)alloc((size_t)N * 4);
    int*            rs    = (int*)alloc((size_t)(N + 1) * 4);
    int*            cursor= (int*)alloc((size_t)N * 4);
    float*          cntf  = (float*)alloc((size_t)N * 4);
    (void)ws_size; (void)n_in; (void)out_size;

    const int PREP_TOT = 3 * 256 * 128 + 256 * 128 + 3 * 128 * 256 + 3 * 128 * 128;
    prep_all_kernel<<<(PREP_TOT + 255) / 256, 256, 0, stream>>>(pm_w1, eh_w1, ph_w1, ph_w2,
                                                                W1abT, EHT, PH1T, PH2T);

    node_enc_kernel<<<(N + 15) / 16, 128, 0, stream>>>(xyr, node_w1, node_b1, node_w2, node_b2, h, hbf, N);
    hipMemsetAsync(cnt, 0, (size_t)N * 4, stream);
    count_kernel<<<(E + 255) / 256, 256, 0, stream>>>(dst, cnt, E);
    scan_kernel<<<1, 1024, 0, stream>>>(cnt, rs, cursor, cntf, N);
    fill_kernel<<<(E + 255) / 256, 256, 0, stream>>>(src, dst, cursor, xyr, esrc, rbfc, E);

    const int MB = (N + 63) / 64;
    for (int l = 0; l < 3; ++l) {
        proj_kernel<<<MB, 256, 0, stream>>>(hbf, W1abT + (size_t)l * 256 * 128, Hs, Hd, N);
        edge_kernel<<<(N + 3) / 4, 256, 0, stream>>>(Hs, Hd, pm_w1 + (size_t)l * 272 * 128 + 256 * 128,
                                                     pm_b1 + l * DH, rs, esrc, rbfc, S, N);
        aggw2_kernel<<<(N + 15) / 16, 128, 0, stream>>>(S, pm_w2 + (size_t)l * 128 * 128,
                                                        pm_b2 + l * DH, cntf, aggbf, N);
        upd_kernel<<<MB, 256, 0, stream>>>(hbf, aggbf, h,
                                           PH1T + (size_t)l * 128 * 256, ph_b1 + l * DH,
                                           PH2T + (size_t)l * 128 * 128, ph_b2 + l * DH,
                                           ln_g + l * DH, ln_b + l * DH, N);
    }

    proj_kernel<<<MB, 256, 0, stream>>>(hbf, EHT, Hs, Hd, N);
    pair_kernel<<<(P + 3) / 4, 256, 0, stream>>>(Hs, Hd, pairs, xyr, eh_w1 + 256 * DH,
                                                 eh_b1, eh_w2, eh_b2, (float*)d_out, P);
}

// Round 6
// 417.137 us; speedup vs baseline: 1.4865x; 1.4666x over previous
//
#include <hip/hip_runtime.h>

#define DH 128

typedef float  floatx4 __attribute__((ext_vector_type(4)));
typedef float  floatx2 __attribute__((ext_vector_type(2)));
typedef short  shortx8 __attribute__((ext_vector_type(8)));
typedef int    intx4  __attribute__((ext_vector_type(4)));

__device__ __forceinline__ unsigned short f2bf(float f) {
    unsigned u = __builtin_bit_cast(unsigned, f);
    u += 0x7fffu + ((u >> 16) & 1u);
    return (unsigned short)(u >> 16);
}
__device__ __forceinline__ float fast_silu(float x) {
    return x * __builtin_amdgcn_rcpf(1.f + __expf(-x));
}

// ---- prep stage 1: W2P[l] = pm_w2[l] @ ph_w1[l][128:256,:]  (f32), cvec[l] = pm_b2[l] @ ph_w1[l][128:256,:] ----
__global__ void prep_w2p_kernel(const float* __restrict__ pm_w2, const float* __restrict__ pm_b2,
                                const float* __restrict__ ph_w1,
                                float* __restrict__ W2P, float* __restrict__ cvec) {
    int idx = blockIdx.x * 256 + threadIdx.x;
    const int tot = 3 * 128 * 128;
    if (idx < tot) {
        int l = idx / (128 * 128);
        int rem = idx - l * 128 * 128;
        int k = rem >> 7, o = rem & 127;
        const float* w2r = pm_w2 + (size_t)l * 128 * 128 + (size_t)k * 128;
        const float* p1b = ph_w1 + (size_t)l * 256 * 128 + (size_t)128 * 128 + o;
        float s = 0.f;
        for (int m = 0; m < 128; ++m) s += w2r[m] * p1b[(size_t)m * 128];
        W2P[idx] = s;
        return;
    }
    idx -= tot;
    if (idx < 3 * 128) {
        int l = idx >> 7, o = idx & 127;
        const float* b2 = pm_b2 + l * 128;
        const float* p1b = ph_w1 + (size_t)l * 256 * 128 + (size_t)128 * 128 + o;
        float s = 0.f;
        for (int m = 0; m < 128; ++m) s += b2[m] * p1b[(size_t)m * 128];
        cvec[idx] = s;
    }
}

// ---- prep stage 2: all bf16 transposed weight mats ----
__global__ void prep_all_kernel(const float* __restrict__ pm_w1, const float* __restrict__ eh_w1,
                                const float* __restrict__ ph_w1, const float* __restrict__ ph_w2,
                                const float* __restrict__ W2P,
                                unsigned short* __restrict__ W1abT, unsigned short* __restrict__ EHT,
                                unsigned short* __restrict__ PB1T, unsigned short* __restrict__ PH2T) {
    int idx = blockIdx.x * 256 + threadIdx.x;
    const int nA = 3 * 256 * 128;
    const int nB = 256 * 128;
    const int nC = 3 * 128 * 256;
    const int nD = 3 * 128 * 128;
    if (idx < nA) {
        int l = idx / (256 * 128);
        int rem = idx - l * 256 * 128;
        int j = rem >> 7, k = rem & 127;
        int srow = ((j >> 7) << 7) + k;
        W1abT[idx] = f2bf(pm_w1[(size_t)l * 272 * 128 + (size_t)srow * 128 + (j & 127)]);
        return;
    }
    idx -= nA;
    if (idx < nB) {
        int j = idx >> 7, k = idx & 127;
        int srow = ((j >> 7) << 7) + k;
        EHT[idx] = f2bf(eh_w1[(size_t)srow * 128 + (j & 127)]);
        return;
    }
    idx -= nB;
    if (idx < nC) {
        int l = idx / (128 * 256);
        int rem = idx - l * 128 * 256;
        int j = rem >> 8, k = rem & 255;
        float v = (k < 128) ? ph_w1[(size_t)l * 256 * 128 + (size_t)k * 128 + j]
                            : W2P[(size_t)l * 128 * 128 + (size_t)(k - 128) * 128 + j];
        PB1T[idx] = f2bf(v);
        return;
    }
    idx -= nC;
    if (idx < nD) {
        int l = idx / (128 * 128);
        int rem = idx - l * 128 * 128;
        int j = rem >> 7, k = rem & 127;
        PH2T[idx] = f2bf(ph_w2[(size_t)l * 128 * 128 + (size_t)k * 128 + j]);
    }
}

// ---- node encoder ----
__global__ __launch_bounds__(128)
void node_enc_kernel(const float* __restrict__ xyr,
                     const float* __restrict__ w1, const float* __restrict__ b1,
                     const float* __restrict__ w2, const float* __restrict__ b2,
                     float* __restrict__ h, unsigned short* __restrict__ hbf, int N) {
    __shared__ float xs[16][3];
    __shared__ float hid[16][DH];
    int n0 = blockIdx.x * 16;
    int t = threadIdx.x;
    if (t < 48) {
        int i = t / 3, j = t - 3 * (t / 3);
        int n = n0 + i; if (n >= N) n = N - 1;
        xs[i][j] = xyr[3 * n + j];
    }
    __syncthreads();
    int col = t;
    float w10 = w1[col], w11 = w1[DH + col], w12 = w1[2 * DH + col];
    float bb = b1[col];
#pragma unroll
    for (int i = 0; i < 16; ++i) {
        float v = bb + xs[i][0] * w10 + xs[i][1] * w11 + xs[i][2] * w12;
        hid[i][col] = fast_silu(v);
    }
    __syncthreads();
    float a[16];
#pragma unroll
    for (int i = 0; i < 16; ++i) a[i] = b2[col];
    for (int j = 0; j < DH; ++j) {
        float wv = w2[j * DH + col];
#pragma unroll
        for (int i = 0; i < 16; ++i) a[i] += hid[i][j] * wv;
    }
    for (int i = 0; i < 16; ++i) {
        int n = n0 + i;
        if (n < N) {
            h[(size_t)n * DH + col] = a[i];
            hbf[(size_t)n * DH + col] = f2bf(a[i]);
        }
    }
}

// ---- CSR build ----
__global__ void count_kernel(const int* __restrict__ dst, int* __restrict__ cnt, int E) {
    int e = blockIdx.x * 256 + threadIdx.x;
    if (e < E) atomicAdd(&cnt[dst[e]], 1);
}
__global__ __launch_bounds__(1024)
void scan_kernel(const int* __restrict__ cnt, int* __restrict__ rs, int* __restrict__ cursor,
                 float* __restrict__ cntf, int N) {
    __shared__ int ps[1024];
    const int CH = 16;
    int t = threadIdx.x;
    int base = t * CH;
    int loc[CH];
    int s = 0;
#pragma unroll
    for (int j = 0; j < CH; ++j) {
        int i = base + j;
        int v = (i < N) ? cnt[i] : 0;
        if (i < N) cntf[i] = (float)v;
        loc[j] = s; s += v;
    }
    ps[t] = s;
    __syncthreads();
    for (int off = 1; off < 1024; off <<= 1) {
        int v = (t >= off) ? ps[t - off] : 0;
        __syncthreads();
        ps[t] += v;
        __syncthreads();
    }
    int pre = (t > 0) ? ps[t - 1] : 0;
#pragma unroll
    for (int j = 0; j < CH; ++j) {
        int i = base + j;
        if (i < N) { int v = pre + loc[j]; rs[i] = v; cursor[i] = v; }
    }
    if (t == 0) rs[N] = ps[1023];
}
// ---- fill + rbf prep fused ----
__global__ void fill_kernel(const int* __restrict__ src, const int* __restrict__ dst,
                            int* __restrict__ cursor, const float* __restrict__ xyr,
                            int* __restrict__ esrc, float* __restrict__ rbfc, int E) {
    int e = blockIdx.x * 256 + threadIdx.x;
    if (e >= E) return;
    int s = src[e], d = dst[e];
    int p = atomicAdd(&cursor[d], 1);
    esrc[p] = s;
    float dx = xyr[3 * s] - xyr[3 * d];
    float dy = xyr[3 * s + 1] - xyr[3 * d + 1];
    float r = sqrtf(dx * dx + dy * dy + 1e-8f);
    const float step = 1.41421356237309515f / 15.f;
    const float gamma = 56.25f;
    float* op = rbfc + (size_t)p * 16;
#pragma unroll
    for (int q = 0; q < 4; ++q) {
        float d0 = r - (4 * q + 0) * step;
        float d1 = r - (4 * q + 1) * step;
        float d2 = r - (4 * q + 2) * step;
        float d3 = r - (4 * q + 3) * step;
        floatx4 o;
        o.x = __expf(-gamma * d0 * d0);
        o.y = __expf(-gamma * d1 * d1);
        o.z = __expf(-gamma * d2 * d2);
        o.w = __expf(-gamma * d3 * d3);
        *(floatx4*)(op + 4 * q) = o;
    }
}

// ---- proj: O1||O2 = Abf @ BT^T  (M x 128 @ 128 x 256), fp32 out ----
__global__ __launch_bounds__(256)
void proj_kernel(const unsigned short* __restrict__ Abf,
                 const unsigned short* __restrict__ BT,
                 float* __restrict__ O1, float* __restrict__ O2, int M) {
    const int tid = threadIdx.x;
    const int w = tid >> 6, lane = tid & 63;
    const int mr = lane & 15, q = lane >> 4;
    const int row0 = blockIdx.x * 64;
    floatx4 acc[4][4] = {};
#pragma unroll
    for (int kc = 0; kc < 4; ++kc) {
        const int ko = kc * 32 + q * 8;
        shortx8 a[4], b[4];
#pragma unroll
        for (int mt = 0; mt < 4; ++mt) {
            int r = row0 + mt * 16 + mr; if (r >= M) r = M - 1;
            a[mt] = *reinterpret_cast<const shortx8*>(Abf + (size_t)r * DH + ko);
        }
#pragma unroll
        for (int nt = 0; nt < 4; ++nt) {
            int ocol = w * 64 + nt * 16 + mr;
            b[nt] = *reinterpret_cast<const shortx8*>(BT + (size_t)ocol * DH + ko);
        }
#pragma unroll
        for (int mt = 0; mt < 4; ++mt)
#pragma unroll
            for (int nt = 0; nt < 4; ++nt)
                acc[mt][nt] = __builtin_amdgcn_mfma_f32_16x16x32_bf16(a[mt], b[nt], acc[mt][nt], 0, 0, 0);
    }
#pragma unroll
    for (int nt = 0; nt < 4; ++nt) {
        int ocol = w * 64 + nt * 16 + mr;
        float* O = (ocol < DH) ? O1 : O2;
        int col = ocol & (DH - 1);
#pragma unroll
        for (int mt = 0; mt < 4; ++mt)
#pragma unroll
            for (int r4 = 0; r4 < 4; ++r4) {
                int gr = row0 + mt * 16 + q * 4 + r4;
                if (gr < M) O[(size_t)gr * DH + col] = acc[mt][nt][r4];
            }
    }
}

// ---- edge stream + aggregate: one wave per node (64-thread block), batch-4,
//      nontemporal streaming loads, Hs cached, S emitted as bf16 ----
__global__ __launch_bounds__(64, 4)
void edge_kernel(const float* __restrict__ Hs, const float* __restrict__ Hd,
                 const float* __restrict__ w1c, const float* __restrict__ b1,
                 const int* __restrict__ rs, const int* __restrict__ esrc,
                 const float* __restrict__ rbfc,
                 unsigned int* __restrict__ Sbf, int N) {
    const int n = blockIdx.x;
    const int lane = threadIdx.x;
    const int c = lane * 2;
    floatx2 wc[16];
#pragma unroll
    for (int k = 0; k < 16; ++k) wc[k] = *(const floatx2*)(w1c + k * DH + c);
    const floatx2* hdp = (const floatx2*)(Hd + (size_t)n * DH + c);
    floatx2 hdn = __builtin_nontemporal_load(hdp) + *(const floatx2*)(b1 + c);
    const int s = rs[n], e = rs[n + 1];
    floatx2 acc = {0.f, 0.f};
    int j = s;
    for (; j + 4 <= e; j += 4) {
        const intx4* sp = (const intx4*)(esrc + j);
        intx4 sn = __builtin_nontemporal_load(sp);
        floatx4 rb[4][4];
#pragma unroll
        for (int i = 0; i < 4; ++i) {
            const floatx4* rp = (const floatx4*)(rbfc + (size_t)(j + i) * 16);
#pragma unroll
            for (int q = 0; q < 4; ++q) rb[i][q] = __builtin_nontemporal_load(rp + q);
        }
        floatx2 hs0 = *(const floatx2*)(Hs + (size_t)sn.x * DH + c);
        floatx2 hs1 = *(const floatx2*)(Hs + (size_t)sn.y * DH + c);
        floatx2 hs2 = *(const floatx2*)(Hs + (size_t)sn.z * DH + c);
        floatx2 hs3 = *(const floatx2*)(Hs + (size_t)sn.w * DH + c);
        floatx2 hsv[4] = {hs0, hs1, hs2, hs3};
#pragma unroll
        for (int i = 0; i < 4; ++i) {
            floatx2 pre = hsv[i] + hdn;
            pre += rb[i][0].x * wc[0];  pre += rb[i][0].y * wc[1];
            pre += rb[i][0].z * wc[2];  pre += rb[i][0].w * wc[3];
            pre += rb[i][1].x * wc[4];  pre += rb[i][1].y * wc[5];
            pre += rb[i][1].z * wc[6];  pre += rb[i][1].w * wc[7];
            pre += rb[i][2].x * wc[8];  pre += rb[i][2].y * wc[9];
            pre += rb[i][2].z * wc[10]; pre += rb[i][2].w * wc[11];
            pre += rb[i][3].x * wc[12]; pre += rb[i][3].y * wc[13];
            pre += rb[i][3].z * wc[14]; pre += rb[i][3].w * wc[15];
            floatx2 sg;
            sg.x = __builtin_amdgcn_rcpf(1.f + __expf(-pre.x));
            sg.y = __builtin_amdgcn_rcpf(1.f + __expf(-pre.y));
            acc += pre * sg;
        }
    }
    for (; j < e; ++j) {
        int sn = esrc[j];
        floatx2 hs = *(const floatx2*)(Hs + (size_t)sn * DH + c);
        const floatx4* rp = (const floatx4*)(rbfc + (size_t)j * 16);
        floatx4 r0 = __builtin_nontemporal_load(rp);
        floatx4 r1 = __builtin_nontemporal_load(rp + 1);
        floatx4 r2 = __builtin_nontemporal_load(rp + 2);
        floatx4 r3 = __builtin_nontemporal_load(rp + 3);
        floatx2 pre = hs + hdn;
        pre += r0.x * wc[0];  pre += r0.y * wc[1];  pre += r0.z * wc[2];  pre += r0.w * wc[3];
        pre += r1.x * wc[4];  pre += r1.y * wc[5];  pre += r1.z * wc[6];  pre += r1.w * wc[7];
        pre += r2.x * wc[8];  pre += r2.y * wc[9];  pre += r2.z * wc[10]; pre += r2.w * wc[11];
        pre += r3.x * wc[12]; pre += r3.y * wc[13]; pre += r3.z * wc[14]; pre += r3.w * wc[15];
        floatx2 sg;
        sg.x = __builtin_amdgcn_rcpf(1.f + __expf(-pre.x));
        sg.y = __builtin_amdgcn_rcpf(1.f + __expf(-pre.y));
        acc += pre * sg;
    }
    unsigned lo = f2bf(acc.x), hi = f2bf(acc.y);
    Sbf[(size_t)n * 64 + lane] = lo | (hi << 16);
}

// ---- node update: pre1 = h@P1a + S@W2P + b1 + cnt*cvec ; silu ; @P2 + b2 + resid ; LN ----
__global__ __launch_bounds__(256)
void upd_kernel(unsigned short* hbf,
                const unsigned short* __restrict__ Sbf16,
                float* h,
                const unsigned short* __restrict__ PB1T,   // [128][256]
                const float* __restrict__ b1v,
                const float* __restrict__ cvec,            // [128]
                const float* __restrict__ cntf,
                const unsigned short* __restrict__ P2T,    // [128][128]
                const float* __restrict__ b2v,
                const float* __restrict__ g, const float* __restrict__ bb,
                int M) {
    __shared__ unsigned short HID[64 * 136];
    __shared__ float red[4][64][2];
    __shared__ float stats[64][2];
    __shared__ float cntL[64];
    const int tid = threadIdx.x;
    const int w = tid >> 6, lane = tid & 63;
    const int mr = lane & 15, q = lane >> 4;
    const int row0 = blockIdx.x * 64;

    if (tid < 64) {
        int r = row0 + tid;
        cntL[tid] = (r < M) ? cntf[r] : 0.f;
    }
    __syncthreads();

    floatx4 acc[4][2] = {};
#pragma unroll
    for (int kc = 0; kc < 8; ++kc) {
        const int ko = kc * 32 + q * 8;
        shortx8 a[4], bfr[2];
#pragma unroll
        for (int mt = 0; mt < 4; ++mt) {
            int r = row0 + mt * 16 + mr; if (r >= M) r = M - 1;
            const unsigned short* sp = (ko < DH) ? (hbf + (size_t)r * DH + ko)
                                                 : (Sbf16 + (size_t)r * DH + (ko - DH));
            a[mt] = *reinterpret_cast<const shortx8*>(sp);
        }
#pragma unroll
        for (int nt = 0; nt < 2; ++nt)
            bfr[nt] = *reinterpret_cast<const shortx8*>(PB1T + (size_t)(w * 32 + nt * 16 + mr) * 256 + ko);
#pragma unroll
        for (int mt = 0; mt < 4; ++mt)
#pragma unroll
            for (int nt = 0; nt < 2; ++nt)
                acc[mt][nt] = __builtin_amdgcn_mfma_f32_16x16x32_bf16(a[mt], bfr[nt], acc[mt][nt], 0, 0, 0);
    }
#pragma unroll
    for (int nt = 0; nt < 2; ++nt) {
        int col = w * 32 + nt * 16 + mr;
        float bv = b1v[col], cv = cvec[col];
#pragma unroll
        for (int mt = 0; mt < 4; ++mt)
#pragma unroll
            for (int r4 = 0; r4 < 4; ++r4) {
                int row = mt * 16 + q * 4 + r4;
                HID[row * 136 + col] = f2bf(fast_silu(acc[mt][nt][r4] + bv + cntL[row] * cv));
            }
    }
    __syncthreads();

    floatx4 acc3[4][2] = {};
#pragma unroll
    for (int kc = 0; kc < 4; ++kc) {
        const int ko = kc * 32 + q * 8;
        shortx8 a[4], bfr[2];
#pragma unroll
        for (int mt = 0; mt < 4; ++mt)
            a[mt] = *reinterpret_cast<const shortx8*>(HID + (mt * 16 + mr) * 136 + ko);
#pragma unroll
        for (int nt = 0; nt < 2; ++nt)
            bfr[nt] = *reinterpret_cast<const shortx8*>(P2T + (size_t)(w * 32 + nt * 16 + mr) * DH + ko);
#pragma unroll
        for (int mt = 0; mt < 4; ++mt)
#pragma unroll
            for (int nt = 0; nt < 2; ++nt)
                acc3[mt][nt] = __builtin_amdgcn_mfma_f32_16x16x32_bf16(a[mt], bfr[nt], acc3[mt][nt], 0, 0, 0);
    }
#pragma unroll
    for (int nt = 0; nt < 2; ++nt) {
        int col = w * 32 + nt * 16 + mr;
        float b2c = b2v[col];
#pragma unroll
        for (int mt = 0; mt < 4; ++mt)
#pragma unroll
            for (int r4 = 0; r4 < 4; ++r4) {
                int gr = row0 + mt * 16 + q * 4 + r4;
                float hv = (gr < M) ? h[(size_t)gr * DH + col] : 0.f;
                acc3[mt][nt][r4] = acc3[mt][nt][r4] + b2c + hv;
            }
    }
#pragma unroll
    for (int mt = 0; mt < 4; ++mt)
#pragma unroll
        for (int r4 = 0; r4 < 4; ++r4) {
            float y0 = acc3[mt][0][r4], y1 = acc3[mt][1][r4];
            float s1 = y0 + y1, s2 = y0 * y0 + y1 * y1;
#pragma unroll
            for (int m = 1; m < 16; m <<= 1) {
                s1 += __shfl_xor(s1, m);
                s2 += __shfl_xor(s2, m);
            }
            if (mr == 0) {
                int row = mt * 16 + q * 4 + r4;
                red[w][row][0] = s1; red[w][row][1] = s2;
            }
        }
    __syncthreads();
    if (tid < 64) {
        float s1 = red[0][tid][0] + red[1][tid][0] + red[2][tid][0] + red[3][tid][0];
        float s2 = red[0][tid][1] + red[1][tid][1] + red[2][tid][1] + red[3][tid][1];
        float mu = s1 * (1.f / DH);
        float var = s2 * (1.f / DH) - mu * mu;
        stats[tid][0] = mu;
        stats[tid][1] = rsqrtf(var + 1e-5f);
    }
    __syncthreads();
#pragma unroll
    for (int nt = 0; nt < 2; ++nt) {
        int col = w * 32 + nt * 16 + mr;
        float gc = g[col], bc = bb[col];
#pragma unroll
        for (int mt = 0; mt < 4; ++mt)
#pragma unroll
            for (int r4 = 0; r4 < 4; ++r4) {
                int row = mt * 16 + q * 4 + r4;
                int gr = row0 + row;
                if (gr < M) {
                    float yv = (acc3[mt][nt][r4] - stats[row][0]) * stats[row][1] * gc + bc;
                    h[(size_t)gr * DH + col] = yv;
                    hbf[(size_t)gr * DH + col] = f2bf(yv);
                }
            }
    }
}

// ---- pair head: one wave per pair ----
__global__ __launch_bounds__(256)
void pair_kernel(const float* __restrict__ Hu, const float* __restrict__ Hv,
                 const int* __restrict__ pairs, const float* __restrict__ xyr,
                 const float* __restrict__ ehw1c,
                 const float* __restrict__ eb1, const float* __restrict__ ew2,
                 const float* __restrict__ eb2,
                 float* __restrict__ out, int P) {
    int w = threadIdx.x >> 6, lane = threadIdx.x & 63;
    int p = blockIdx.x * 4 + w;
    if (p >= P) return;
    int u = pairs[2 * p], v = pairs[2 * p + 1];
    float ru = xyr[3 * u + 2], rv = xyr[3 * v + 2];
    float dx = xyr[3 * u] - xyr[3 * v];
    float dy = xyr[3 * u + 1] - xyr[3 * v + 1];
    float dist = sqrtf(dx * dx + dy * dy + 1e-8f);
    float adr = fabsf(ru - rv);
    int c = lane * 2;
    float2 hu = *(const float2*)(Hu + (size_t)u * DH + c);
    float2 hv = *(const float2*)(Hv + (size_t)v * DH + c);
    float2 bv = *(const float2*)(eb1 + c);
    float2 wv = *(const float2*)(ew2 + c);
    float2 c0 = *(const float2*)(ehw1c + 0 * DH + c);
    float2 c1 = *(const float2*)(ehw1c + 1 * DH + c);
    float2 c2 = *(const float2*)(ehw1c + 2 * DH + c);
    float2 c3 = *(const float2*)(ehw1c + 3 * DH + c);
    float px = hu.x + hv.x + bv.x + ru * c0.x + rv * c1.x + dist * c2.x + adr * c3.x;
    float py = hu.y + hv.y + bv.y + ru * c0.y + rv * c1.y + dist * c2.y + adr * c3.y;
    float val = fast_silu(px) * wv.x + fast_silu(py) * wv.y;
#pragma unroll
    for (int m = 1; m < 64; m <<= 1) val += __shfl_xor(val, m);
    if (lane == 0) out[p] = val + eb2[0];
}

extern "C" void kernel_launch(void* const* d_in, const int* in_sizes, int n_in,
                              void* d_out, int out_size, void* d_ws, size_t ws_size,
                              hipStream_t stream) {
    const float* xyr     = (const float*)d_in[0];
    const int*   eidx    = (const int*)d_in[1];
    const int*   pairs   = (const int*)d_in[2];
    const float* node_w1 = (const float*)d_in[3];
    const float* node_b1 = (const float*)d_in[4];
    const float* node_w2 = (const float*)d_in[5];
    const float* node_b2 = (const float*)d_in[6];
    const float* pm_w1   = (const float*)d_in[7];
    const float* pm_b1   = (const float*)d_in[8];
    const float* pm_w2   = (const float*)d_in[9];
    const float* pm_b2   = (const float*)d_in[10];
    const float* ph_w1   = (const float*)d_in[11];
    const float* ph_b1   = (const float*)d_in[12];
    const float* ph_w2   = (const float*)d_in[13];
    const float* ph_b2   = (const float*)d_in[14];
    const float* ln_g    = (const float*)d_in[15];
    const float* ln_b    = (const float*)d_in[16];
    const float* eh_w1   = (const float*)d_in[17];
    const float* eh_b1   = (const float*)d_in[18];
    const float* eh_w2   = (const float*)d_in[19];
    const float* eh_b2   = (const float*)d_in[20];

    const int N = in_sizes[0] / 3;
    const int E = in_sizes[1] / 2;
    const int P = in_sizes[2] / 2;
    const int* src = eidx;
    const int* dst = eidx + E;

    char* ws = (char*)d_ws;
    size_t off = 0;
    auto alloc = [&](size_t bytes) -> char* {
        char* p = ws + off;
        off += (bytes + 255) & ~(size_t)255;
        return p;
    };
    unsigned short* W1abT = (unsigned short*)alloc((size_t)3 * 256 * 128 * 2);
    unsigned short* PB1T  = (unsigned short*)alloc((size_t)3 * 128 * 256 * 2);
    unsigned short* PH2T  = (unsigned short*)alloc((size_t)3 * 128 * 128 * 2);
    unsigned short* EHT   = (unsigned short*)alloc((size_t)256 * 128 * 2);
    float*          W2P   = (float*)alloc((size_t)3 * 128 * 128 * 4);
    float*          cvec  = (float*)alloc((size_t)3 * 128 * 4);
    float*          h     = (float*)alloc((size_t)N * DH * 4);
    unsigned short* hbf   = (unsigned short*)alloc((size_t)N * DH * 2);
    float*          Hs    = (float*)alloc((size_t)N * DH * 4);
    float*          Hd    = (float*)alloc((size_t)N * DH * 4);
    unsigned int*   Sbf   = (unsigned int*)alloc((size_t)N * 64 * 4);
    float*          rbfc  = (float*)alloc((size_t)E * 16 * 4);
    int*            esrc  = (int*)alloc((size_t)E * 4);
    int*            cnt   = (int*)alloc((size_t)N * 4);
    int*            rs    = (int*)alloc((size_t)(N + 1) * 4);
    int*            cursor= (int*)alloc((size_t)N * 4);
    float*          cntf  = (float*)alloc((size_t)N * 4);
    (void)ws_size; (void)n_in; (void)out_size;

    const int W2P_TOT = 3 * 128 * 128 + 3 * 128;
    prep_w2p_kernel<<<(W2P_TOT + 255) / 256, 256, 0, stream>>>(pm_w2, pm_b2, ph_w1, W2P, cvec);
    const int PREP_TOT = 3 * 256 * 128 + 256 * 128 + 3 * 128 * 256 + 3 * 128 * 128;
    prep_all_kernel<<<(PREP_TOT + 255) / 256, 256, 0, stream>>>(pm_w1, eh_w1, ph_w1, ph_w2, W2P,
                                                                W1abT, EHT, PB1T, PH2T);

    node_enc_kernel<<<(N + 15) / 16, 128, 0, stream>>>(xyr, node_w1, node_b1, node_w2, node_b2, h, hbf, N);
    hipError_t _e = hipMemsetAsync(cnt, 0, (size_t)N * 4, stream); (void)_e;
    count_kernel<<<(E + 255) / 256, 256, 0, stream>>>(dst, cnt, E);
    scan_kernel<<<1, 1024, 0, stream>>>(cnt, rs, cursor, cntf, N);
    fill_kernel<<<(E + 255) / 256, 256, 0, stream>>>(src, dst, cursor, xyr, esrc, rbfc, E);

    const int MB = (N + 63) / 64;
    for (int l = 0; l < 3; ++l) {
        proj_kernel<<<MB, 256, 0, stream>>>(hbf, W1abT + (size_t)l * 256 * 128, Hs, Hd, N);
        edge_kernel<<<N, 64, 0, stream>>>(Hs, Hd, pm_w1 + (size_t)l * 272 * 128 + 256 * 128,
                                          pm_b1 + l * DH, rs, esrc, rbfc, Sbf, N);
        upd_kernel<<<MB, 256, 0, stream>>>(hbf, (const unsigned short*)Sbf, h,
                                           PB1T + (size_t)l * 128 * 256, ph_b1 + l * DH,
                                           cvec + l * 128, cntf,
                                           PH2T + (size_t)l * 128 * 128, ph_b2 + l * DH,
                                           ln_g + l * DH, ln_b + l * DH, N);
    }

    proj_kernel<<<MB, 256, 0, stream>>>(hbf, EHT, Hs, Hd, N);
    pair_kernel<<<(P + 3) / 4, 256, 0, stream>>>(Hs, Hd, pairs, xyr, eh_w1 + 256 * DH,
                                                 eh_b1, eh_w2, eh_b2, (float*)d_out, P);
}

// Round 7
// 411.420 us; speedup vs baseline: 1.5071x; 1.0139x over previous
//
#include <hip/hip_runtime.h>

#define DH 128

typedef float  floatx4 __attribute__((ext_vector_type(4)));
typedef float  floatx2 __attribute__((ext_vector_type(2)));
typedef short  shortx8 __attribute__((ext_vector_type(8)));
typedef int    intx4  __attribute__((ext_vector_type(4)));

__device__ __forceinline__ unsigned short f2bf(float f) {
    unsigned u = __builtin_bit_cast(unsigned, f);
    u += 0x7fffu + ((u >> 16) & 1u);
    return (unsigned short)(u >> 16);
}
__device__ __forceinline__ float fast_silu(float x) {
    return x * __builtin_amdgcn_rcpf(1.f + __expf(-x));
}

// ---- prep stage 1: W2P[l] = pm_w2[l] @ ph_w1[l][128:256,:], cvec[l] = pm_b2[l] @ ph_w1[l][128:256,:] ----
__global__ void prep_w2p_kernel(const float* __restrict__ pm_w2, const float* __restrict__ pm_b2,
                                const float* __restrict__ ph_w1,
                                float* __restrict__ W2P, float* __restrict__ cvec) {
    int idx = blockIdx.x * 256 + threadIdx.x;
    const int tot = 3 * 128 * 128;
    if (idx < tot) {
        int l = idx / (128 * 128);
        int rem = idx - l * 128 * 128;
        int k = rem >> 7, o = rem & 127;
        const float* w2r = pm_w2 + (size_t)l * 128 * 128 + (size_t)k * 128;
        const float* p1b = ph_w1 + (size_t)l * 256 * 128 + (size_t)128 * 128 + o;
        float s = 0.f;
        for (int m = 0; m < 128; ++m) s += w2r[m] * p1b[(size_t)m * 128];
        W2P[idx] = s;
        return;
    }
    idx -= tot;
    if (idx < 3 * 128) {
        int l = idx >> 7, o = idx & 127;
        const float* b2 = pm_b2 + l * 128;
        const float* p1b = ph_w1 + (size_t)l * 256 * 128 + (size_t)128 * 128 + o;
        float s = 0.f;
        for (int m = 0; m < 128; ++m) s += b2[m] * p1b[(size_t)m * 128];
        cvec[idx] = s;
    }
}

// ---- prep stage 2: all bf16 transposed weight mats + zero cnt ----
__global__ void prep_all_kernel(const float* __restrict__ pm_w1, const float* __restrict__ eh_w1,
                                const float* __restrict__ ph_w1, const float* __restrict__ ph_w2,
                                const float* __restrict__ W2P,
                                unsigned short* __restrict__ W1abT, unsigned short* __restrict__ EHT,
                                unsigned short* __restrict__ PB1T, unsigned short* __restrict__ PH2T,
                                int* __restrict__ cnt, int N) {
    int idx = blockIdx.x * 256 + threadIdx.x;
    const int nA = 3 * 256 * 128;
    const int nB = 256 * 128;
    const int nC = 3 * 128 * 256;
    const int nD = 3 * 128 * 128;
    if (idx < nA) {
        int l = idx / (256 * 128);
        int rem = idx - l * 256 * 128;
        int j = rem >> 7, k = rem & 127;
        int srow = ((j >> 7) << 7) + k;
        W1abT[idx] = f2bf(pm_w1[(size_t)l * 272 * 128 + (size_t)srow * 128 + (j & 127)]);
        return;
    }
    idx -= nA;
    if (idx < nB) {
        int j = idx >> 7, k = idx & 127;
        int srow = ((j >> 7) << 7) + k;
        EHT[idx] = f2bf(eh_w1[(size_t)srow * 128 + (j & 127)]);
        return;
    }
    idx -= nB;
    if (idx < nC) {
        int l = idx / (128 * 256);
        int rem = idx - l * 128 * 256;
        int j = rem >> 8, k = rem & 255;
        float v = (k < 128) ? ph_w1[(size_t)l * 256 * 128 + (size_t)k * 128 + j]
                            : W2P[(size_t)l * 128 * 128 + (size_t)(k - 128) * 128 + j];
        PB1T[idx] = f2bf(v);
        return;
    }
    idx -= nC;
    if (idx < nD) {
        int l = idx / (128 * 128);
        int rem = idx - l * 128 * 128;
        int j = rem >> 7, k = rem & 127;
        PH2T[idx] = f2bf(ph_w2[(size_t)l * 128 * 128 + (size_t)k * 128 + j]);
        return;
    }
    idx -= nD;
    if (idx < N) cnt[idx] = 0;
}

// ---- node encoder ----
__global__ __launch_bounds__(128)
void node_enc_kernel(const float* __restrict__ xyr,
                     const float* __restrict__ w1, const float* __restrict__ b1,
                     const float* __restrict__ w2, const float* __restrict__ b2,
                     float* __restrict__ h, unsigned short* __restrict__ hbf, int N) {
    __shared__ float xs[16][3];
    __shared__ float hid[16][DH];
    int n0 = blockIdx.x * 16;
    int t = threadIdx.x;
    if (t < 48) {
        int i = t / 3, j = t - 3 * (t / 3);
        int n = n0 + i; if (n >= N) n = N - 1;
        xs[i][j] = xyr[3 * n + j];
    }
    __syncthreads();
    int col = t;
    float w10 = w1[col], w11 = w1[DH + col], w12 = w1[2 * DH + col];
    float bb = b1[col];
#pragma unroll
    for (int i = 0; i < 16; ++i) {
        float v = bb + xs[i][0] * w10 + xs[i][1] * w11 + xs[i][2] * w12;
        hid[i][col] = fast_silu(v);
    }
    __syncthreads();
    float a[16];
#pragma unroll
    for (int i = 0; i < 16; ++i) a[i] = b2[col];
    for (int j = 0; j < DH; ++j) {
        float wv = w2[j * DH + col];
#pragma unroll
        for (int i = 0; i < 16; ++i) a[i] += hid[i][j] * wv;
    }
    for (int i = 0; i < 16; ++i) {
        int n = n0 + i;
        if (n < N) {
            h[(size_t)n * DH + col] = a[i];
            hbf[(size_t)n * DH + col] = f2bf(a[i]);
        }
    }
}

// ---- CSR build ----
__global__ void count_kernel(const int* __restrict__ dst, int* __restrict__ cnt, int E) {
    int e = blockIdx.x * 256 + threadIdx.x;
    if (e < E) atomicAdd(&cnt[dst[e]], 1);
}
__global__ __launch_bounds__(1024)
void scan_kernel(const int* __restrict__ cnt, int* __restrict__ rs, int* __restrict__ cursor,
                 float* __restrict__ cntf, int N) {
    __shared__ int ps[1024];
    const int CH = 16;
    int t = threadIdx.x;
    int base = t * CH;
    int loc[CH];
    int s = 0;
#pragma unroll
    for (int j = 0; j < CH; ++j) {
        int i = base + j;
        int v = (i < N) ? cnt[i] : 0;
        if (i < N) cntf[i] = (float)v;
        loc[j] = s; s += v;
    }
    ps[t] = s;
    __syncthreads();
    for (int off = 1; off < 1024; off <<= 1) {
        int v = (t >= off) ? ps[t - off] : 0;
        __syncthreads();
        ps[t] += v;
        __syncthreads();
    }
    int pre = (t > 0) ? ps[t - 1] : 0;
#pragma unroll
    for (int j = 0; j < CH; ++j) {
        int i = base + j;
        if (i < N) { int v = pre + loc[j]; rs[i] = v; cursor[i] = v; }
    }
    if (t == 0) rs[N] = ps[1023];
}
// ---- fill + rbf prep fused; pads esrc[E..E+15]=0 so edge tail batches stay vectorized ----
__global__ void fill_kernel(const int* __restrict__ src, const int* __restrict__ dst,
                            int* __restrict__ cursor, const float* __restrict__ xyr,
                            int* __restrict__ esrc, float* __restrict__ rbfc, int E) {
    int e = blockIdx.x * 256 + threadIdx.x;
    if (e < 16) esrc[E + e] = 0;
    if (e >= E) return;
    int s = src[e], d = dst[e];
    int p = atomicAdd(&cursor[d], 1);
    esrc[p] = s;
    float dx = xyr[3 * s] - xyr[3 * d];
    float dy = xyr[3 * s + 1] - xyr[3 * d + 1];
    float r = sqrtf(dx * dx + dy * dy + 1e-8f);
    const float step = 1.41421356237309515f / 15.f;
    const float gamma = 56.25f;
    float* op = rbfc + (size_t)p * 16;
#pragma unroll
    for (int q = 0; q < 4; ++q) {
        float d0 = r - (4 * q + 0) * step;
        float d1 = r - (4 * q + 1) * step;
        float d2 = r - (4 * q + 2) * step;
        float d3 = r - (4 * q + 3) * step;
        floatx4 o;
        o.x = __expf(-gamma * d0 * d0);
        o.y = __expf(-gamma * d1 * d1);
        o.z = __expf(-gamma * d2 * d2);
        o.w = __expf(-gamma * d3 * d3);
        *(floatx4*)(op + 4 * q) = o;
    }
}

// ---- proj (layer-0 only): O1||O2 = Abf @ BT^T ----
__global__ __launch_bounds__(256)
void proj_kernel(const unsigned short* __restrict__ Abf,
                 const unsigned short* __restrict__ BT,
                 float* __restrict__ O1, float* __restrict__ O2, int M) {
    const int tid = threadIdx.x;
    const int w = tid >> 6, lane = tid & 63;
    const int mr = lane & 15, q = lane >> 4;
    const int row0 = blockIdx.x * 64;
    floatx4 acc[4][4] = {};
#pragma unroll
    for (int kc = 0; kc < 4; ++kc) {
        const int ko = kc * 32 + q * 8;
        shortx8 a[4], b[4];
#pragma unroll
        for (int mt = 0; mt < 4; ++mt) {
            int r = row0 + mt * 16 + mr; if (r >= M) r = M - 1;
            a[mt] = *reinterpret_cast<const shortx8*>(Abf + (size_t)r * DH + ko);
        }
#pragma unroll
        for (int nt = 0; nt < 4; ++nt) {
            int ocol = w * 64 + nt * 16 + mr;
            b[nt] = *reinterpret_cast<const shortx8*>(BT + (size_t)ocol * DH + ko);
        }
#pragma unroll
        for (int mt = 0; mt < 4; ++mt)
#pragma unroll
            for (int nt = 0; nt < 4; ++nt)
                acc[mt][nt] = __builtin_amdgcn_mfma_f32_16x16x32_bf16(a[mt], b[nt], acc[mt][nt], 0, 0, 0);
    }
#pragma unroll
    for (int nt = 0; nt < 4; ++nt) {
        int ocol = w * 64 + nt * 16 + mr;
        float* O = (ocol < DH) ? O1 : O2;
        int col = ocol & (DH - 1);
#pragma unroll
        for (int mt = 0; mt < 4; ++mt)
#pragma unroll
            for (int r4 = 0; r4 < 4; ++r4) {
                int gr = row0 + mt * 16 + q * 4 + r4;
                if (gr < M) O[(size_t)gr * DH + col] = acc[mt][nt][r4];
            }
    }
}

// ---- edge stream + aggregate: one wave per node, explicit 2-deep esrc / 1-deep Hs pipeline ----
__global__ __launch_bounds__(64)
void edge_kernel(const float* __restrict__ Hs, const float* __restrict__ Hd,
                 const float* __restrict__ w1c, const float* __restrict__ b1,
                 const int* __restrict__ rs, const int* __restrict__ esrc,
                 const float* __restrict__ rbfc,
                 unsigned int* __restrict__ Sbf, int N) {
    const int n = blockIdx.x;
    const int lane = threadIdx.x;
    const int c = lane * 2;
    floatx2 wc[16];
#pragma unroll
    for (int k = 0; k < 16; ++k) wc[k] = *(const floatx2*)(w1c + k * DH + c);
    const floatx2* hdp = (const floatx2*)(Hd + (size_t)n * DH + c);
    floatx2 hdn = __builtin_nontemporal_load(hdp) + *(const floatx2*)(b1 + c);
    const int s = rs[n], e = rs[n + 1];
    floatx2 acc = {0.f, 0.f};
    const int cnt = e - s;
    if (cnt > 0) {
        const int nb = (cnt + 3) >> 2;
        intx4 snB = __builtin_nontemporal_load((const intx4*)(esrc + s));
        intx4 snC = __builtin_nontemporal_load((const intx4*)(esrc + s + 4));
        floatx2 hs[4];
        hs[0] = *(const floatx2*)(Hs + (size_t)snB.x * DH + c);
        hs[1] = *(const floatx2*)(Hs + (size_t)snB.y * DH + c);
        hs[2] = *(const floatx2*)(Hs + (size_t)snB.z * DH + c);
        hs[3] = *(const floatx2*)(Hs + (size_t)snB.w * DH + c);
        snB = snC;
        for (int b = 0; b < nb; ++b) {
            const int j = s + b * 4;
            snC = __builtin_nontemporal_load((const intx4*)(esrc + j + 8));
            floatx2 hsn[4];
            hsn[0] = *(const floatx2*)(Hs + (size_t)snB.x * DH + c);
            hsn[1] = *(const floatx2*)(Hs + (size_t)snB.y * DH + c);
            hsn[2] = *(const floatx2*)(Hs + (size_t)snB.z * DH + c);
            hsn[3] = *(const floatx2*)(Hs + (size_t)snB.w * DH + c);
            floatx2 pre[4];
#pragma unroll
            for (int i = 0; i < 4; ++i) pre[i] = hs[i] + hdn;
#pragma unroll
            for (int qc = 0; qc < 4; ++qc) {
                floatx4 r0 = __builtin_nontemporal_load((const floatx4*)(rbfc + (size_t)(j + 0) * 16 + qc * 4));
                floatx4 r1 = __builtin_nontemporal_load((const floatx4*)(rbfc + (size_t)(j + 1) * 16 + qc * 4));
                floatx4 r2 = __builtin_nontemporal_load((const floatx4*)(rbfc + (size_t)(j + 2) * 16 + qc * 4));
                floatx4 r3 = __builtin_nontemporal_load((const floatx4*)(rbfc + (size_t)(j + 3) * 16 + qc * 4));
                pre[0] += r0.x * wc[4 * qc + 0]; pre[0] += r0.y * wc[4 * qc + 1];
                pre[0] += r0.z * wc[4 * qc + 2]; pre[0] += r0.w * wc[4 * qc + 3];
                pre[1] += r1.x * wc[4 * qc + 0]; pre[1] += r1.y * wc[4 * qc + 1];
                pre[1] += r1.z * wc[4 * qc + 2]; pre[1] += r1.w * wc[4 * qc + 3];
                pre[2] += r2.x * wc[4 * qc + 0]; pre[2] += r2.y * wc[4 * qc + 1];
                pre[2] += r2.z * wc[4 * qc + 2]; pre[2] += r2.w * wc[4 * qc + 3];
                pre[3] += r3.x * wc[4 * qc + 0]; pre[3] += r3.y * wc[4 * qc + 1];
                pre[3] += r3.z * wc[4 * qc + 2]; pre[3] += r3.w * wc[4 * qc + 3];
            }
#pragma unroll
            for (int i = 0; i < 4; ++i) {
                floatx2 sg;
                sg.x = __builtin_amdgcn_rcpf(1.f + __expf(-pre[i].x));
                sg.y = __builtin_amdgcn_rcpf(1.f + __expf(-pre[i].y));
                float msk = (j + i < e) ? 1.f : 0.f;
                acc += (pre[i] * sg) * msk;
            }
#pragma unroll
            for (int i = 0; i < 4; ++i) hs[i] = hsn[i];
            snB = snC;
        }
    }
    unsigned lo = f2bf(acc.x), hi = f2bf(acc.y);
    Sbf[(size_t)n * 64 + lane] = lo | (hi << 16);
}

// ---- node update + fused next-layer projection ----
// pre1 = h@P1a + S@W2P + b1 + cnt*cvec ; silu ; @P2 + b2 + resid ; LN -> h,hbf
// then (post-LN rows)@BT -> O1,O2  (BT = next layer W1abT, or EHT for last layer)
__global__ __launch_bounds__(256)
void upd_kernel(unsigned short* hbf,
                const unsigned short* __restrict__ Sbf16,
                float* h,
                const unsigned short* __restrict__ PB1T,   // [128][256]
                const float* __restrict__ b1v,
                const float* __restrict__ cvec,            // [128]
                const float* __restrict__ cntf,
                const unsigned short* __restrict__ P2T,    // [128][128]
                const float* __restrict__ b2v,
                const float* __restrict__ g, const float* __restrict__ bb,
                const unsigned short* __restrict__ BT,     // [256][128] next-proj
                float* __restrict__ O1, float* __restrict__ O2,
                int M) {
    __shared__ unsigned short HID[64 * 136];
    __shared__ float red[4][64][2];
    __shared__ float stats[64][2];
    __shared__ float cntL[64];
    const int tid = threadIdx.x;
    const int w = tid >> 6, lane = tid & 63;
    const int mr = lane & 15, q = lane >> 4;
    const int row0 = blockIdx.x * 64;

    if (tid < 64) {
        int r = row0 + tid;
        cntL[tid] = (r < M) ? cntf[r] : 0.f;
    }
    __syncthreads();

    floatx4 acc[4][2] = {};
#pragma unroll
    for (int kc = 0; kc < 8; ++kc) {
        const int ko = kc * 32 + q * 8;
        shortx8 a[4], bfr[2];
#pragma unroll
        for (int mt = 0; mt < 4; ++mt) {
            int r = row0 + mt * 16 + mr; if (r >= M) r = M - 1;
            const unsigned short* sp = (ko < DH) ? (hbf + (size_t)r * DH + ko)
                                                 : (Sbf16 + (size_t)r * DH + (ko - DH));
            a[mt] = *reinterpret_cast<const shortx8*>(sp);
        }
#pragma unroll
        for (int nt = 0; nt < 2; ++nt)
            bfr[nt] = *reinterpret_cast<const shortx8*>(PB1T + (size_t)(w * 32 + nt * 16 + mr) * 256 + ko);
#pragma unroll
        for (int mt = 0; mt < 4; ++mt)
#pragma unroll
            for (int nt = 0; nt < 2; ++nt)
                acc[mt][nt] = __builtin_amdgcn_mfma_f32_16x16x32_bf16(a[mt], bfr[nt], acc[mt][nt], 0, 0, 0);
    }
#pragma unroll
    for (int nt = 0; nt < 2; ++nt) {
        int col = w * 32 + nt * 16 + mr;
        float bv = b1v[col], cv = cvec[col];
#pragma unroll
        for (int mt = 0; mt < 4; ++mt)
#pragma unroll
            for (int r4 = 0; r4 < 4; ++r4) {
                int row = mt * 16 + q * 4 + r4;
                HID[row * 136 + col] = f2bf(fast_silu(acc[mt][nt][r4] + bv + cntL[row] * cv));
            }
    }
    __syncthreads();

    floatx4 acc3[4][2] = {};
#pragma unroll
    for (int kc = 0; kc < 4; ++kc) {
        const int ko = kc * 32 + q * 8;
        shortx8 a[4], bfr[2];
#pragma unroll
        for (int mt = 0; mt < 4; ++mt)
            a[mt] = *reinterpret_cast<const shortx8*>(HID + (mt * 16 + mr) * 136 + ko);
#pragma unroll
        for (int nt = 0; nt < 2; ++nt)
            bfr[nt] = *reinterpret_cast<const shortx8*>(P2T + (size_t)(w * 32 + nt * 16 + mr) * DH + ko);
#pragma unroll
        for (int mt = 0; mt < 4; ++mt)
#pragma unroll
            for (int nt = 0; nt < 2; ++nt)
                acc3[mt][nt] = __builtin_amdgcn_mfma_f32_16x16x32_bf16(a[mt], bfr[nt], acc3[mt][nt], 0, 0, 0);
    }
#pragma unroll
    for (int nt = 0; nt < 2; ++nt) {
        int col = w * 32 + nt * 16 + mr;
        float b2c = b2v[col];
#pragma unroll
        for (int mt = 0; mt < 4; ++mt)
#pragma unroll
            for (int r4 = 0; r4 < 4; ++r4) {
                int gr = row0 + mt * 16 + q * 4 + r4;
                float hv = (gr < M) ? h[(size_t)gr * DH + col] : 0.f;
                acc3[mt][nt][r4] = acc3[mt][nt][r4] + b2c + hv;
            }
    }
#pragma unroll
    for (int mt = 0; mt < 4; ++mt)
#pragma unroll
        for (int r4 = 0; r4 < 4; ++r4) {
            float y0 = acc3[mt][0][r4], y1 = acc3[mt][1][r4];
            float s1 = y0 + y1, s2 = y0 * y0 + y1 * y1;
#pragma unroll
            for (int m = 1; m < 16; m <<= 1) {
                s1 += __shfl_xor(s1, m);
                s2 += __shfl_xor(s2, m);
            }
            if (mr == 0) {
                int row = mt * 16 + q * 4 + r4;
                red[w][row][0] = s1; red[w][row][1] = s2;
            }
        }
    __syncthreads();
    if (tid < 64) {
        float s1 = red[0][tid][0] + red[1][tid][0] + red[2][tid][0] + red[3][tid][0];
        float s2 = red[0][tid][1] + red[1][tid][1] + red[2][tid][1] + red[3][tid][1];
        float mu = s1 * (1.f / DH);
        float var = s2 * (1.f / DH) - mu * mu;
        stats[tid][0] = mu;
        stats[tid][1] = rsqrtf(var + 1e-5f);
    }
    __syncthreads();
#pragma unroll
    for (int nt = 0; nt < 2; ++nt) {
        int col = w * 32 + nt * 16 + mr;
        float gc = g[col], bc = bb[col];
#pragma unroll
        for (int mt = 0; mt < 4; ++mt)
#pragma unroll
            for (int r4 = 0; r4 < 4; ++r4) {
                int row = mt * 16 + q * 4 + r4;
                int gr = row0 + row;
                if (gr < M) {
                    float yv = (acc3[mt][nt][r4] - stats[row][0]) * stats[row][1] * gc + bc;
                    unsigned short yb = f2bf(yv);
                    h[(size_t)gr * DH + col] = yv;
                    hbf[(size_t)gr * DH + col] = yb;
                    HID[row * 136 + col] = yb;   // stage for fused proj
                }
            }
    }
    __syncthreads();

    // fused proj: HID(64x128 post-LN bf16) @ BT^T (256x128) -> O1||O2
    floatx4 acc4[4][4] = {};
#pragma unroll
    for (int kc = 0; kc < 4; ++kc) {
        const int ko = kc * 32 + q * 8;
        shortx8 a[4], b[4];
#pragma unroll
        for (int mt = 0; mt < 4; ++mt)
            a[mt] = *reinterpret_cast<const shortx8*>(HID + (mt * 16 + mr) * 136 + ko);
#pragma unroll
        for (int nt = 0; nt < 4; ++nt) {
            int ocol = w * 64 + nt * 16 + mr;
            b[nt] = *reinterpret_cast<const shortx8*>(BT + (size_t)ocol * DH + ko);
        }
#pragma unroll
        for (int mt = 0; mt < 4; ++mt)
#pragma unroll
            for (int nt = 0; nt < 4; ++nt)
                acc4[mt][nt] = __builtin_amdgcn_mfma_f32_16x16x32_bf16(a[mt], b[nt], acc4[mt][nt], 0, 0, 0);
    }
#pragma unroll
    for (int nt = 0; nt < 4; ++nt) {
        int ocol = w * 64 + nt * 16 + mr;
        float* O = (ocol < DH) ? O1 : O2;
        int col = ocol & (DH - 1);
#pragma unroll
        for (int mt = 0; mt < 4; ++mt)
#pragma unroll
            for (int r4 = 0; r4 < 4; ++r4) {
                int gr = row0 + mt * 16 + q * 4 + r4;
                if (gr < M) O[(size_t)gr * DH + col] = acc4[mt][nt][r4];
            }
    }
}

// ---- pair head: one wave per pair ----
__global__ __launch_bounds__(256)
void pair_kernel(const float* __restrict__ Hu, const float* __restrict__ Hv,
                 const int* __restrict__ pairs, const float* __restrict__ xyr,
                 const float* __restrict__ ehw1c,
                 const float* __restrict__ eb1, const float* __restrict__ ew2,
                 const float* __restrict__ eb2,
                 float* __restrict__ out, int P) {
    int w = threadIdx.x >> 6, lane = threadIdx.x & 63;
    int p = blockIdx.x * 4 + w;
    if (p >= P) return;
    int u = pairs[2 * p], v = pairs[2 * p + 1];
    float ru = xyr[3 * u + 2], rv = xyr[3 * v + 2];
    float dx = xyr[3 * u] - xyr[3 * v];
    float dy = xyr[3 * u + 1] - xyr[3 * v + 1];
    float dist = sqrtf(dx * dx + dy * dy + 1e-8f);
    float adr = fabsf(ru - rv);
    int c = lane * 2;
    float2 hu = *(const float2*)(Hu + (size_t)u * DH + c);
    float2 hv = *(const float2*)(Hv + (size_t)v * DH + c);
    float2 bv = *(const float2*)(eb1 + c);
    float2 wv = *(const float2*)(ew2 + c);
    float2 c0 = *(const float2*)(ehw1c + 0 * DH + c);
    float2 c1 = *(const float2*)(ehw1c + 1 * DH + c);
    float2 c2 = *(const float2*)(ehw1c + 2 * DH + c);
    float2 c3 = *(const float2*)(ehw1c + 3 * DH + c);
    float px = hu.x + hv.x + bv.x + ru * c0.x + rv * c1.x + dist * c2.x + adr * c3.x;
    float py = hu.y + hv.y + bv.y + ru * c0.y + rv * c1.y + dist * c2.y + adr * c3.y;
    float val = fast_silu(px) * wv.x + fast_silu(py) * wv.y;
#pragma unroll
    for (int m = 1; m < 64; m <<= 1) val += __shfl_xor(val, m);
    if (lane == 0) out[p] = val + eb2[0];
}

extern "C" void kernel_launch(void* const* d_in, const int* in_sizes, int n_in,
                              void* d_out, int out_size, void* d_ws, size_t ws_size,
                              hipStream_t stream) {
    const float* xyr     = (const float*)d_in[0];
    const int*   eidx    = (const int*)d_in[1];
    const int*   pairs   = (const int*)d_in[2];
    const float* node_w1 = (const float*)d_in[3];
    const float* node_b1 = (const float*)d_in[4];
    const float* node_w2 = (const float*)d_in[5];
    const float* node_b2 = (const float*)d_in[6];
    const float* pm_w1   = (const float*)d_in[7];
    const float* pm_b1   = (const float*)d_in[8];
    const float* pm_w2   = (const float*)d_in[9];
    const float* pm_b2   = (const float*)d_in[10];
    const float* ph_w1   = (const float*)d_in[11];
    const float* ph_b1   = (const float*)d_in[12];
    const float* ph_w2   = (const float*)d_in[13];
    const float* ph_b2   = (const float*)d_in[14];
    const float* ln_g    = (const float*)d_in[15];
    const float* ln_b    = (const float*)d_in[16];
    const float* eh_w1   = (const float*)d_in[17];
    const float* eh_b1   = (const float*)d_in[18];
    const float* eh_w2   = (const float*)d_in[19];
    const float* eh_b2   = (const float*)d_in[20];

    const int N = in_sizes[0] / 3;
    const int E = in_sizes[1] / 2;
    const int P = in_sizes[2] / 2;
    const int* src = eidx;
    const int* dst = eidx + E;

    char* ws = (char*)d_ws;
    size_t off = 0;
    auto alloc = [&](size_t bytes) -> char* {
        char* p = ws + off;
        off += (bytes + 255) & ~(size_t)255;
        return p;
    };
    unsigned short* W1abT = (unsigned short*)alloc((size_t)3 * 256 * 128 * 2);
    unsigned short* PB1T  = (unsigned short*)alloc((size_t)3 * 128 * 256 * 2);
    unsigned short* PH2T  = (unsigned short*)alloc((size_t)3 * 128 * 128 * 2);
    unsigned short* EHT   = (unsigned short*)alloc((size_t)256 * 128 * 2);
    float*          W2P   = (float*)alloc((size_t)3 * 128 * 128 * 4);
    float*          cvec  = (float*)alloc((size_t)3 * 128 * 4);
    float*          h     = (float*)alloc((size_t)N * DH * 4);
    unsigned short* hbf   = (unsigned short*)alloc((size_t)N * DH * 2);
    float*          Hs    = (float*)alloc((size_t)N * DH * 4);
    float*          Hd    = (float*)alloc((size_t)N * DH * 4);
    unsigned int*   Sbf   = (unsigned int*)alloc((size_t)N * 64 * 4);
    float*          rbfc  = (float*)alloc((size_t)(E + 16) * 16 * 4);
    int*            esrc  = (int*)alloc((size_t)(E + 16) * 4);
    int*            cnt   = (int*)alloc((size_t)N * 4);
    int*            rs    = (int*)alloc((size_t)(N + 1) * 4);
    int*            cursor= (int*)alloc((size_t)N * 4);
    float*          cntf  = (float*)alloc((size_t)N * 4);
    (void)ws_size; (void)n_in; (void)out_size;

    const int W2P_TOT = 3 * 128 * 128 + 3 * 128;
    prep_w2p_kernel<<<(W2P_TOT + 255) / 256, 256, 0, stream>>>(pm_w2, pm_b2, ph_w1, W2P, cvec);
    const int PREP_TOT = 3 * 256 * 128 + 256 * 128 + 3 * 128 * 256 + 3 * 128 * 128 + N;
    prep_all_kernel<<<(PREP_TOT + 255) / 256, 256, 0, stream>>>(pm_w1, eh_w1, ph_w1, ph_w2, W2P,
                                                                W1abT, EHT, PB1T, PH2T, cnt, N);

    node_enc_kernel<<<(N + 15) / 16, 128, 0, stream>>>(xyr, node_w1, node_b1, node_w2, node_b2, h, hbf, N);
    count_kernel<<<(E + 255) / 256, 256, 0, stream>>>(dst, cnt, E);
    scan_kernel<<<1, 1024, 0, stream>>>(cnt, rs, cursor, cntf, N);
    fill_kernel<<<(E + 255) / 256, 256, 0, stream>>>(src, dst, cursor, xyr, esrc, rbfc, E);

    const int MB = (N + 63) / 64;
    proj_kernel<<<MB, 256, 0, stream>>>(hbf, W1abT, Hs, Hd, N);
    for (int l = 0; l < 3; ++l) {
        const unsigned short* BT = (l < 2) ? (W1abT + (size_t)(l + 1) * 256 * 128) : EHT;
        edge_kernel<<<N, 64, 0, stream>>>(Hs, Hd, pm_w1 + (size_t)l * 272 * 128 + 256 * 128,
                                          pm_b1 + l * DH, rs, esrc, rbfc, Sbf, N);
        upd_kernel<<<MB, 256, 0, stream>>>(hbf, (const unsigned short*)Sbf, h,
                                           PB1T + (size_t)l * 128 * 256, ph_b1 + l * DH,
                                           cvec + l * 128, cntf,
                                           PH2T + (size_t)l * 128 * 128, ph_b2 + l * DH,
                                           ln_g + l * DH, ln_b + l * DH,
                                           BT, Hs, Hd, N);
    }

    pair_kernel<<<(P + 3) / 4, 256, 0, stream>>>(Hs, Hd, pairs, xyr, eh_w1 + 256 * DH,
                                                 eh_b1, eh_w2, eh_b2, (float*)d_out, P);
}